// Round 1
// baseline (2116.722 us; speedup 1.0000x reference)
//
#include <hip/hip_runtime.h>
#include <math.h>

#define HW 65536
#define WD 256
#define HT 256

__device__ __forceinline__ int iclamp(int v, int lo, int hi) {
    return v < lo ? lo : (v > hi ? hi : v);
}

struct Taps {
    int i00, i01, i10, i11;
    float w00, w01, w10, w11;
};

__device__ __forceinline__ Taps make_taps(float py, float px) {
    float fy0 = floorf(py), fx0 = floorf(px);
    float wy = py - fy0, wx = px - fx0;
    int y0 = (int)fy0, x0 = (int)fx0;
    int y1 = y0 + 1, x1 = x0 + 1;
    float vy0 = (y0 >= 0 && y0 <= HT - 1) ? 1.f : 0.f;
    float vy1 = (y1 >= 0 && y1 <= HT - 1) ? 1.f : 0.f;
    float vx0 = (x0 >= 0 && x0 <= WD - 1) ? 1.f : 0.f;
    float vx1 = (x1 >= 0 && x1 <= WD - 1) ? 1.f : 0.f;
    int yc0 = iclamp(y0, 0, HT - 1), yc1 = iclamp(y1, 0, HT - 1);
    int xc0 = iclamp(x0, 0, WD - 1), xc1 = iclamp(x1, 0, WD - 1);
    Taps t;
    t.i00 = yc0 * WD + xc0; t.i01 = yc0 * WD + xc1;
    t.i10 = yc1 * WD + xc0; t.i11 = yc1 * WD + xc1;
    t.w00 = (1.f - wy) * (1.f - wx) * vy0 * vx0;
    t.w01 = (1.f - wy) * wx * vy0 * vx1;
    t.w10 = wy * (1.f - wx) * vy1 * vx0;
    t.w11 = wy * wx * vy1 * vx1;
    return t;
}

// ---------------------------------------------------------------------------
// Kernel 1: bilinear warp of nbr by optical flow. 1 thread = 1 (b,y,x),
// loops 64 channels. Coalesced writes; gathers are spatially local.
// ---------------------------------------------------------------------------
__global__ __launch_bounds__(256) void warp_kernel(
    const float* __restrict__ nbr, const float* __restrict__ flow,
    float* __restrict__ wout)
{
    int t = blockIdx.x * 256 + threadIdx.x;   // 0 .. B*HW-1
    int b = t >> 16;
    int pos = t & (HW - 1);
    int yy = pos >> 8, xx = pos & 255;
    float fx = flow[b * 2 * HW + pos];        // channel 0 = x
    float fy = flow[b * 2 * HW + HW + pos];   // channel 1 = y
    Taps tp = make_taps((float)yy + fy, (float)xx + fx);
    const float* nb = nbr + b * 64 * HW;
    float* wo = wout + b * 64 * HW + pos;
    #pragma unroll 8
    for (int c = 0; c < 64; ++c) {
        const float* pc = nb + c * HW;
        wo[c * HW] = tp.w00 * pc[tp.i00] + tp.w01 * pc[tp.i01] +
                     tp.w10 * pc[tp.i10] + tp.w11 * pc[tp.i11];
    }
}

// ---------------------------------------------------------------------------
// Generic direct 3x3 same-conv. Input channels come from two sources:
// srcA (first CA channels) and srcB (remaining CIN-CA channels), both
// laid out (b, ch, H, W). Block = 64 pixels x OGC out-channel groups.
// Each thread: 1 pixel, OGS out channels. Input chunk staged in LDS.
// Weight address is wave-uniform (readfirstlane) -> scalar loads.
// ---------------------------------------------------------------------------
template <int CIN, int CA, int COUT, int OGC, int OGS, int CHUNK, bool RELU>
__global__ __launch_bounds__(64 * OGC) void conv3x3_kernel(
    const float* __restrict__ srcA, const float* __restrict__ srcB,
    const float* __restrict__ wgt, const float* __restrict__ bias,
    float* __restrict__ dst)
{
    const int tid = threadIdx.x;
    const int p = tid & 63;
    const int og = __builtin_amdgcn_readfirstlane(tid >> 6); // wave-uniform
    const int blk = blockIdx.x;
    const int xseg = blk & 3;            // W/64 = 4 segments
    const int yy = (blk >> 2) & 255;
    const int b = blk >> 10;
    const int x0 = xseg * 64;

    __shared__ float lds[CHUNK * 3 * 66];

    const int ochbase = og * OGS;
    float acc[OGS];
    #pragma unroll
    for (int o = 0; o < OGS; ++o) acc[o] = bias[ochbase + o];

    const float* pA = srcA + b * CA * HW;
    const float* pB = srcB + b * (CIN - CA) * HW;

    #pragma unroll 1
    for (int j = 0; j < CIN / CHUNK; ++j) {
        const int c0 = j * CHUNK;
        // ---- stage input chunk: [CHUNK][3 rows][66 pixels], zero-padded
        for (int i = tid; i < CHUNK * 3 * 66; i += 64 * OGC) {
            int c = i / (3 * 66);
            int rem = i % (3 * 66);
            int r = rem / 66;
            int xx = rem % 66;
            int gy = yy + r - 1;
            int gx = x0 + xx - 1;
            float v = 0.f;
            if (gy >= 0 && gy < HT && gx >= 0 && gx < WD) {
                int cc = c0 + c;
                v = (cc < CA) ? pA[cc * HW + gy * WD + gx]
                              : pB[(cc - CA) * HW + gy * WD + gx];
            }
            lds[i] = v;
        }
        __syncthreads();

        // ---- per-thread input registers (stride-1 LDS reads: conflict-free)
        float in_reg[CHUNK * 9];
        #pragma unroll
        for (int c = 0; c < CHUNK; ++c)
            #pragma unroll
            for (int r = 0; r < 3; ++r)
                #pragma unroll
                for (int kx = 0; kx < 3; ++kx)
                    in_reg[(c * 3 + r) * 3 + kx] = lds[(c * 3 + r) * 66 + p + kx];

        // ---- FMA block: weights are wave-uniform -> s_load path
        #pragma unroll
        for (int o = 0; o < OGS; ++o) {
            const float* wp = wgt + ((ochbase + o) * CIN + c0) * 9;
            #pragma unroll
            for (int i = 0; i < CHUNK * 9; ++i)
                acc[o] = fmaf(in_reg[i], wp[i], acc[o]);
        }
        __syncthreads();
    }

    float* outp = dst + (long)b * COUT * HW + yy * WD + x0 + p;
    #pragma unroll
    for (int o = 0; o < OGS; ++o) {
        float v = acc[o];
        if (RELU) v = fmaxf(v, 0.f);
        outp[(ochbase + o) * HW] = v;
    }
}

// ---------------------------------------------------------------------------
// Repack dcn_w (o, ic=g*8+c, ky, kx) -> w2[g][k][c][o] so the DCN inner
// loop reads 64 contiguous wave-uniform floats per (g,k,c).
// ---------------------------------------------------------------------------
__global__ __launch_bounds__(256) void repack_dcn_kernel(
    const float* __restrict__ w, float* __restrict__ w2)
{
    int t = blockIdx.x * 256 + threadIdx.x;   // 36864 total
    int o = t & 63;
    int c = (t >> 6) & 7;
    int gk = t >> 9;          // 0..71
    int k = gk % 9;
    int g = gk / 9;
    w2[t] = w[(o * 64 + g * 8 + c) * 9 + k];
}

// ---------------------------------------------------------------------------
// Kernel 4: deformable sampling + grouped einsum + bias.
// 1 thread = 1 (b,y,x); 64 fp32 accumulators. Offsets/mask read from the
// raw om-conv output (flow add + sigmoid applied on the fly; the big
// offset/mask tensor is never materialized separately).
// ---------------------------------------------------------------------------
__global__ __launch_bounds__(256) void dcn_kernel(
    const float* __restrict__ raw,    // (B,216,HW) om-conv output
    const float* __restrict__ flow,   // (B,2,HW)
    const float* __restrict__ nbr,    // (B,64,HW)
    const float* __restrict__ w2,     // [g][k][c][o] = 8*9*8*64
    const float* __restrict__ bias,   // 64
    float* __restrict__ out)          // (B,64,HW)
{
    int t = blockIdx.x * 256 + threadIdx.x;
    int b = t >> 16;
    int pos = t & (HW - 1);
    int yy = pos >> 8, xx = pos & 255;

    const float* rawb = raw + (long)b * 216 * HW + pos;
    float fx = flow[b * 2 * HW + pos];
    float fy = flow[b * 2 * HW + HW + pos];
    const float* nb = nbr + b * 64 * HW;

    float acc[64];
    #pragma unroll
    for (int o = 0; o < 64; ++o) acc[o] = bias[o];

    #pragma unroll 1
    for (int g = 0; g < 8; ++g) {
        const float* nbg = nb + g * 8 * HW;
        #pragma unroll 1
        for (int k = 0; k < 9; ++k) {
            // offset channels: dy = g*18+2k, dx = g*18+2k+1; mask = 144+g*9+k
            float dy = rawb[(g * 18 + 2 * k) * HW] + fy;
            float dx = rawb[(g * 18 + 2 * k + 1) * HW] + fx;
            float mr = rawb[(144 + g * 9 + k) * HW];
            float m = 1.f / (1.f + __expf(-mr));

            float py = (float)(yy - 1 + k / 3) + dy;
            float px = (float)(xx - 1 + k % 3) + dx;
            Taps tp = make_taps(py, px);
            // fold mask into tap weights
            float w00 = tp.w00 * m, w01 = tp.w01 * m;
            float w10 = tp.w10 * m, w11 = tp.w11 * m;

            float s[8];
            #pragma unroll
            for (int c = 0; c < 8; ++c) {
                const float* pc = nbg + c * HW;
                s[c] = w00 * pc[tp.i00] + w01 * pc[tp.i01] +
                       w10 * pc[tp.i10] + w11 * pc[tp.i11];
            }

            const float* wp = w2 + (g * 9 + k) * 512;  // [c][o] contiguous
            #pragma unroll
            for (int c = 0; c < 8; ++c) {
                float sc = s[c];
                #pragma unroll
                for (int o = 0; o < 64; ++o)
                    acc[o] = fmaf(sc, wp[c * 64 + o], acc[o]);
            }
        }
    }

    float* op = out + (long)b * 64 * HW + pos;
    #pragma unroll
    for (int o = 0; o < 64; ++o) op[o * HW] = acc[o];
}

// ---------------------------------------------------------------------------
extern "C" void kernel_launch(void* const* d_in, const int* in_sizes, int n_in,
                              void* d_out, int out_size, void* d_ws, size_t ws_size,
                              hipStream_t stream)
{
    const float* nbr  = (const float*)d_in[0];   // (2,64,256,256)
    const float* ref  = (const float*)d_in[1];   // (2,64,256,256)
    const float* flow = (const float*)d_in[2];   // (2,2,256,256)
    const float* c1w  = (const float*)d_in[3];   // (64,128,3,3)
    const float* c1b  = (const float*)d_in[4];   // (64)
    const float* omw  = (const float*)d_in[5];   // (216,66,3,3)
    const float* omb  = (const float*)d_in[6];   // (216)
    const float* dw   = (const float*)d_in[7];   // (64,64,3,3)
    const float* db   = (const float*)d_in[8];   // (64)
    float* out = (float*)d_out;

    float* ws = (float*)d_ws;
    float* warp  = ws;                       // 2*64*65536  = 8388608
    float* fea   = warp + 8388608;           // 2*64*65536  = 8388608
    float* omraw = fea + 8388608;            // 2*216*65536 = 28311552
    float* w2    = omraw + 28311552;         // 36864

    repack_dcn_kernel<<<144, 256, 0, stream>>>(dw, w2);
    warp_kernel<<<512, 256, 0, stream>>>(nbr, flow, warp);
    // conv1: 128 -> 64, srcA = warp (64 ch), srcB = ref (64 ch), ReLU
    conv3x3_kernel<128, 64, 64, 4, 16, 8, true>
        <<<2048, 256, 0, stream>>>(warp, ref, c1w, c1b, fea);
    // om-conv: 66 -> 216, srcA = fea (64 ch), srcB = flow (2 ch)
    conv3x3_kernel<66, 64, 216, 4, 54, 6, false>
        <<<2048, 256, 0, stream>>>(fea, flow, omw, omb, omraw);
    dcn_kernel<<<512, 256, 0, stream>>>(omraw, flow, nbr, w2, db, out);
}

// Round 2
// 1959.263 us; speedup vs baseline: 1.0804x; 1.0804x over previous
//
#include <hip/hip_runtime.h>
#include <math.h>

#define HW 65536
#define WD 256
#define HT 256

__device__ __forceinline__ int iclamp(int v, int lo, int hi) {
    return v < lo ? lo : (v > hi ? hi : v);
}

struct Taps {
    int i00, i01, i10, i11;
    float w00, w01, w10, w11;
};

__device__ __forceinline__ Taps make_taps(float py, float px) {
    float fy0 = floorf(py), fx0 = floorf(px);
    float wy = py - fy0, wx = px - fx0;
    int y0 = (int)fy0, x0 = (int)fx0;
    int y1 = y0 + 1, x1 = x0 + 1;
    float vy0 = (y0 >= 0 && y0 <= HT - 1) ? 1.f : 0.f;
    float vy1 = (y1 >= 0 && y1 <= HT - 1) ? 1.f : 0.f;
    float vx0 = (x0 >= 0 && x0 <= WD - 1) ? 1.f : 0.f;
    float vx1 = (x1 >= 0 && x1 <= WD - 1) ? 1.f : 0.f;
    int yc0 = iclamp(y0, 0, HT - 1), yc1 = iclamp(y1, 0, HT - 1);
    int xc0 = iclamp(x0, 0, WD - 1), xc1 = iclamp(x1, 0, WD - 1);
    Taps t;
    t.i00 = yc0 * WD + xc0; t.i01 = yc0 * WD + xc1;
    t.i10 = yc1 * WD + xc0; t.i11 = yc1 * WD + xc1;
    t.w00 = (1.f - wy) * (1.f - wx) * vy0 * vx0;
    t.w01 = (1.f - wy) * wx * vy0 * vx1;
    t.w10 = wy * (1.f - wx) * vy1 * vx0;
    t.w11 = wy * wx * vy1 * vx1;
    return t;
}

// ---------------------------------------------------------------------------
// Kernel 1: bilinear warp of nbr by optical flow.
// ---------------------------------------------------------------------------
__global__ __launch_bounds__(256) void warp_kernel(
    const float* __restrict__ nbr, const float* __restrict__ flow,
    float* __restrict__ wout)
{
    int t = blockIdx.x * 256 + threadIdx.x;   // 0 .. B*HW-1
    int b = t >> 16;
    int pos = t & (HW - 1);
    int yy = pos >> 8, xx = pos & 255;
    float fx = flow[b * 2 * HW + pos];        // channel 0 = x
    float fy = flow[b * 2 * HW + HW + pos];   // channel 1 = y
    Taps tp = make_taps((float)yy + fy, (float)xx + fx);
    const float* nb = nbr + b * 64 * HW;
    float* wo = wout + b * 64 * HW + pos;
    #pragma unroll 8
    for (int c = 0; c < 64; ++c) {
        const float* pc = nb + c * HW;
        wo[c * HW] = tp.w00 * pc[tp.i00] + tp.w01 * pc[tp.i01] +
                     tp.w10 * pc[tp.i10] + tp.w11 * pc[tp.i11];
    }
}

// ---------------------------------------------------------------------------
// Generic direct 3x3 same-conv, spill-free loop order:
//   for c in CHUNK:  load 9 input taps -> regs
//     for o in OGS:  9 FMAs (weights wave-uniform -> s_load path)
// Registers: acc[OGS] + in9[9] + addressing. No CHUNK-scaled reg arrays.
// Block = 64 pixels x OGC out-channel waves; each thread 1 px, OGS out ch.
// ---------------------------------------------------------------------------
template <int CIN, int CA, int COUT, int OGC, int OGS, int CHUNK, bool RELU>
__global__ __launch_bounds__(64 * OGC) void conv3x3_kernel(
    const float* __restrict__ srcA, const float* __restrict__ srcB,
    const float* __restrict__ wgt, const float* __restrict__ bias,
    float* __restrict__ dst)
{
    const int tid = threadIdx.x;
    const int p = tid & 63;
    const int og = __builtin_amdgcn_readfirstlane(tid >> 6); // wave-uniform
    const int blk = blockIdx.x;
    const int xseg = blk & 3;            // W/64 = 4 segments
    const int yy = (blk >> 2) & 255;
    const int b = blk >> 10;
    const int x0 = xseg * 64;

    __shared__ float lds[CHUNK * 3 * 66];

    const int ochbase = og * OGS;
    float acc[OGS];
    #pragma unroll
    for (int o = 0; o < OGS; ++o) acc[o] = bias[ochbase + o];

    const float* pA = srcA + b * CA * HW;
    const float* pB = srcB + b * (CIN - CA) * HW;

    #pragma unroll 1
    for (int j = 0; j < CIN / CHUNK; ++j) {
        const int c0 = j * CHUNK;
        // ---- stage input chunk: [CHUNK][3 rows][66 pixels], zero-padded
        for (int i = tid; i < CHUNK * 3 * 66; i += 64 * OGC) {
            int c = i / (3 * 66);
            int rem = i % (3 * 66);
            int r = rem / 66;
            int xx = rem % 66;
            int gy = yy + r - 1;
            int gx = x0 + xx - 1;
            float v = 0.f;
            if (gy >= 0 && gy < HT && gx >= 0 && gx < WD) {
                int cc = c0 + c;
                v = (cc < CA) ? pA[cc * HW + gy * WD + gx]
                              : pB[(cc - CA) * HW + gy * WD + gx];
            }
            lds[i] = v;
        }
        __syncthreads();

        // ---- per input channel: 9 taps -> regs, then OGS x 9 FMAs
        #pragma unroll 1
        for (int c = 0; c < CHUNK; ++c) {
            float in9[9];
            #pragma unroll
            for (int r = 0; r < 3; ++r)
                #pragma unroll
                for (int kx = 0; kx < 3; ++kx)
                    in9[r * 3 + kx] = lds[(c * 3 + r) * 66 + p + kx];

            const int cc = c0 + c;
            #pragma unroll
            for (int o = 0; o < OGS; ++o) {
                const float* wp = wgt + ((ochbase + o) * CIN + cc) * 9;
                #pragma unroll
                for (int i = 0; i < 9; ++i)
                    acc[o] = fmaf(in9[i], wp[i], acc[o]);
            }
        }
        __syncthreads();
    }

    float* outp = dst + (long)b * COUT * HW + yy * WD + x0 + p;
    #pragma unroll
    for (int o = 0; o < OGS; ++o) {
        float v = acc[o];
        if (RELU) v = fmaxf(v, 0.f);
        outp[(ochbase + o) * HW] = v;
    }
}

// ---------------------------------------------------------------------------
// Repack dcn_w (o, ic=g*8+c, ky, kx) -> w2[g][k][c][o]
// ---------------------------------------------------------------------------
__global__ __launch_bounds__(256) void repack_dcn_kernel(
    const float* __restrict__ w, float* __restrict__ w2)
{
    int t = blockIdx.x * 256 + threadIdx.x;   // 36864 total
    int o = t & 63;
    int c = (t >> 6) & 7;
    int gk = t >> 9;          // 0..71
    int k = gk % 9;
    int g = gk / 9;
    w2[t] = w[(o * 64 + g * 8 + c) * 9 + k];
}

// ---------------------------------------------------------------------------
// Kernel 4: deformable sampling + grouped einsum + bias.
// ---------------------------------------------------------------------------
__global__ __launch_bounds__(256) void dcn_kernel(
    const float* __restrict__ raw,    // (B,216,HW) om-conv output
    const float* __restrict__ flow,   // (B,2,HW)
    const float* __restrict__ nbr,    // (B,64,HW)
    const float* __restrict__ w2,     // [g][k][c][o] = 8*9*8*64
    const float* __restrict__ bias,   // 64
    float* __restrict__ out)          // (B,64,HW)
{
    int t = blockIdx.x * 256 + threadIdx.x;
    int b = t >> 16;
    int pos = t & (HW - 1);
    int yy = pos >> 8, xx = pos & 255;

    const float* rawb = raw + (long)b * 216 * HW + pos;
    float fx = flow[b * 2 * HW + pos];
    float fy = flow[b * 2 * HW + HW + pos];
    const float* nb = nbr + b * 64 * HW;

    float acc[64];
    #pragma unroll
    for (int o = 0; o < 64; ++o) acc[o] = bias[o];

    #pragma unroll 1
    for (int g = 0; g < 8; ++g) {
        const float* nbg = nb + g * 8 * HW;
        #pragma unroll 1
        for (int k = 0; k < 9; ++k) {
            // offset channels: dy = g*18+2k, dx = g*18+2k+1; mask = 144+g*9+k
            float dy = rawb[(g * 18 + 2 * k) * HW] + fy;
            float dx = rawb[(g * 18 + 2 * k + 1) * HW] + fx;
            float mr = rawb[(144 + g * 9 + k) * HW];
            float m = 1.f / (1.f + __expf(-mr));

            float py = (float)(yy - 1 + k / 3) + dy;
            float px = (float)(xx - 1 + k % 3) + dx;
            Taps tp = make_taps(py, px);
            float w00 = tp.w00 * m, w01 = tp.w01 * m;
            float w10 = tp.w10 * m, w11 = tp.w11 * m;

            float s[8];
            #pragma unroll
            for (int c = 0; c < 8; ++c) {
                const float* pc = nbg + c * HW;
                s[c] = w00 * pc[tp.i00] + w01 * pc[tp.i01] +
                       w10 * pc[tp.i10] + w11 * pc[tp.i11];
            }

            const float* wp = w2 + (g * 9 + k) * 512;  // [c][o] contiguous
            #pragma unroll
            for (int c = 0; c < 8; ++c) {
                float sc = s[c];
                #pragma unroll
                for (int o = 0; o < 64; ++o)
                    acc[o] = fmaf(sc, wp[c * 64 + o], acc[o]);
            }
        }
    }

    float* op = out + (long)b * 64 * HW + pos;
    #pragma unroll
    for (int o = 0; o < 64; ++o) op[o * HW] = acc[o];
}

// ---------------------------------------------------------------------------
extern "C" void kernel_launch(void* const* d_in, const int* in_sizes, int n_in,
                              void* d_out, int out_size, void* d_ws, size_t ws_size,
                              hipStream_t stream)
{
    const float* nbr  = (const float*)d_in[0];   // (2,64,256,256)
    const float* ref  = (const float*)d_in[1];   // (2,64,256,256)
    const float* flow = (const float*)d_in[2];   // (2,2,256,256)
    const float* c1w  = (const float*)d_in[3];   // (64,128,3,3)
    const float* c1b  = (const float*)d_in[4];   // (64)
    const float* omw  = (const float*)d_in[5];   // (216,66,3,3)
    const float* omb  = (const float*)d_in[6];   // (216)
    const float* dw   = (const float*)d_in[7];   // (64,64,3,3)
    const float* db   = (const float*)d_in[8];   // (64)
    float* out = (float*)d_out;

    float* ws = (float*)d_ws;
    float* warp  = ws;                       // 2*64*65536  = 8388608
    float* fea   = warp + 8388608;           // 2*64*65536  = 8388608
    float* omraw = fea + 8388608;            // 2*216*65536 = 28311552
    float* w2    = omraw + 28311552;         // 36864

    repack_dcn_kernel<<<144, 256, 0, stream>>>(dw, w2);
    warp_kernel<<<512, 256, 0, stream>>>(nbr, flow, warp);
    // conv1: 128 -> 64, srcA = warp (64 ch), srcB = ref (64 ch), ReLU
    // OGS=16: acc[16]+in9[9] -> no spill. CHUNK=16 -> 8 barrier iters.
    conv3x3_kernel<128, 64, 64, 4, 16, 16, true>
        <<<2048, 256, 0, stream>>>(warp, ref, c1w, c1b, fea);
    // om-conv: 66 -> 216. OGS=54: acc[54]+in9[9] -> ~80 VGPR, no spill.
    // CHUNK=11 -> 6 barrier iters.
    conv3x3_kernel<66, 64, 216, 4, 54, 11, false>
        <<<2048, 256, 0, stream>>>(fea, flow, omw, omb, omraw);
    dcn_kernel<<<512, 256, 0, stream>>>(omraw, flow, nbr, w2, db, out);
}

// Round 3
// 647.133 us; speedup vs baseline: 3.2709x; 3.0276x over previous
//
#include <hip/hip_runtime.h>
#include <math.h>

#define HW 65536
#define WD 256
#define HT 256

typedef short short8 __attribute__((ext_vector_type(8)));
typedef float f32x4 __attribute__((ext_vector_type(4)));

__device__ __forceinline__ short f2bf(float f) {
    union { float f; unsigned u; } v; v.f = f;
    unsigned r = (v.u + 0x7fffu + ((v.u >> 16) & 1u)) >> 16;
    return (short)r;
}

__device__ __forceinline__ int iclamp(int v, int lo, int hi) {
    return v < lo ? lo : (v > hi ? hi : v);
}

struct Taps {
    int i00, i01, i10, i11;
    float w00, w01, w10, w11;
};

__device__ __forceinline__ Taps make_taps(float py, float px) {
    float fy0 = floorf(py), fx0 = floorf(px);
    float wy = py - fy0, wx = px - fx0;
    int y0 = (int)fy0, x0 = (int)fx0;
    int y1 = y0 + 1, x1 = x0 + 1;
    float vy0 = (y0 >= 0 && y0 <= HT - 1) ? 1.f : 0.f;
    float vy1 = (y1 >= 0 && y1 <= HT - 1) ? 1.f : 0.f;
    float vx0 = (x0 >= 0 && x0 <= WD - 1) ? 1.f : 0.f;
    float vx1 = (x1 >= 0 && x1 <= WD - 1) ? 1.f : 0.f;
    int yc0 = iclamp(y0, 0, HT - 1), yc1 = iclamp(y1, 0, HT - 1);
    int xc0 = iclamp(x0, 0, WD - 1), xc1 = iclamp(x1, 0, WD - 1);
    Taps t;
    t.i00 = yc0 * WD + xc0; t.i01 = yc0 * WD + xc1;
    t.i10 = yc1 * WD + xc0; t.i11 = yc1 * WD + xc1;
    t.w00 = (1.f - wy) * (1.f - wx) * vy0 * vx0;
    t.w01 = (1.f - wy) * wx * vy0 * vx1;
    t.w10 = wy * (1.f - wx) * vy1 * vx0;
    t.w11 = wy * wx * vy1 * vx1;
    return t;
}

// ---------------------------------------------------------------------------
// pack_x1: warp(nbr) + ref -> X1 (B,HW,128) NHWC bf16, via LDS transpose.
// Block = 256 thr = 64 pixels x 4 channel-quarters.
// ---------------------------------------------------------------------------
__global__ __launch_bounds__(256) void pack_x1_kernel(
    const float* __restrict__ nbr, const float* __restrict__ ref,
    const float* __restrict__ flow, short* __restrict__ X1)
{
    __shared__ short tile[64 * 130];   // [px][130] pad to break banks
    int blk = blockIdx.x;              // b*1024 + grp
    int b = blk >> 10;
    int grp = blk & 1023;
    int px = threadIdx.x & 63;
    int qq = threadIdx.x >> 6;
    int pos = grp * 64 + px;
    int yy = pos >> 8, xx = pos & 255;

    float fx = flow[b * 2 * HW + pos];
    float fy = flow[b * 2 * HW + HW + pos];
    Taps tp = make_taps((float)yy + fy, (float)xx + fx);

    const float* nb = nbr + (size_t)b * 64 * HW;
    const float* rf = ref + (size_t)b * 64 * HW;
    #pragma unroll
    for (int j = 0; j < 16; ++j) {
        int c = qq * 16 + j;
        const float* pc = nb + c * HW;
        float v = tp.w00 * pc[tp.i00] + tp.w01 * pc[tp.i01] +
                  tp.w10 * pc[tp.i10] + tp.w11 * pc[tp.i11];
        tile[px * 130 + c] = f2bf(v);
        tile[px * 130 + 64 + c] = f2bf(rf[c * HW + pos]);
    }
    __syncthreads();

    short* xo = X1 + ((size_t)b * HW + grp * 64) * 128;
    #pragma unroll
    for (int f8 = threadIdx.x; f8 < 1024; f8 += 256) {
        int p = (f8 * 8) >> 7;       // pixel
        int c = (f8 * 8) & 127;      // channel
        short8 v;
        #pragma unroll
        for (int j = 0; j < 8; ++j) v[j] = tile[p * 130 + c + j];
        *(short8*)(xo + f8 * 8) = v;
    }
}

// ---------------------------------------------------------------------------
// pack_x2_flow: fill X2 channels 64..95 (flow bf16 + zero pad). 1 thr/pixel.
// ---------------------------------------------------------------------------
__global__ __launch_bounds__(256) void pack_x2_flow_kernel(
    const float* __restrict__ flow, short* __restrict__ X2)
{
    int t = blockIdx.x * 256 + threadIdx.x;   // 2*HW
    int b = t >> 16;
    int pos = t & (HW - 1);
    short bx = f2bf(flow[b * 2 * HW + pos]);
    short by = f2bf(flow[b * 2 * HW + HW + pos]);
    short* p = X2 + ((size_t)b * HW + pos) * 96 + 64;
    short8 first = {bx, by, 0, 0, 0, 0, 0, 0};
    short8 z = {0, 0, 0, 0, 0, 0, 0, 0};
    *(short8*)(p) = first;
    *(short8*)(p + 8) = z;
    *(short8*)(p + 16) = z;
    *(short8*)(p + 24) = z;
}

// ---------------------------------------------------------------------------
// Weight repack to MFMA B-fragment order:
//   flat = (((kc*NT + nt)*16 + l)*4 + q)*8 + j ;  k = kc*32 + q*8 + j
// conv1: k = rs*128 + c (rs=k>>7), NT=4, n = nt*16+l, src (64,128,3,3)
// ---------------------------------------------------------------------------
__global__ __launch_bounds__(256) void repack_w1_kernel(
    const float* __restrict__ w, short* __restrict__ wr)
{
    int t = blockIdx.x * 256 + threadIdx.x;  // 73728 = 36<<11
    int j = t & 7, q = (t >> 3) & 3, l = (t >> 5) & 15;
    int nt = (t >> 9) & 3, kc = t >> 11;
    int k = kc * 32 + q * 8 + j;
    int rs = k >> 7, c = k & 127;
    int n = nt * 16 + l;
    wr[t] = f2bf(w[(n * 128 + c) * 9 + rs]);
}

// om: k = rs*96 + c, NT=16 (COUT pad 216->256), CIN pad 66->96
__global__ __launch_bounds__(256) void repack_w2_kernel(
    const float* __restrict__ w, short* __restrict__ wr)
{
    int t = blockIdx.x * 256 + threadIdx.x;  // 221184 = 27<<13
    int j = t & 7, q = (t >> 3) & 3, l = (t >> 5) & 15;
    int nt = (t >> 9) & 15, kc = t >> 13;
    int k = kc * 32 + q * 8 + j;
    int rs = k / 96, c = k % 96;
    int n = nt * 16 + l;
    float v = (n < 216 && c < 66) ? w[(n * 66 + c) * 9 + rs] : 0.f;
    wr[t] = f2bf(v);
}

// ---------------------------------------------------------------------------
// conv1 MFMA: X1 (NHWC bf16, 128ch) -> fea channels 0..63 of X2 (NHWC bf16,
// stride 96), ReLU. Block: 64px x 64ch, 4 waves = 4 n-tiles, K = 36 chunks.
// ---------------------------------------------------------------------------
#define PADC1 136
__global__ __launch_bounds__(256) void conv1_mfma_kernel(
    const short* __restrict__ X1, const float* __restrict__ bias,
    const short* __restrict__ wr, short* __restrict__ X2)
{
    __shared__ short lds[3 * 66 * PADC1];   // 53,856 B
    const int tid = threadIdx.x;
    const int w = __builtin_amdgcn_readfirstlane(tid >> 6);
    const int l15 = tid & 15;
    const int q = (tid >> 4) & 3;
    const int blk = blockIdx.x;
    const int xseg = blk & 3;
    const int yy = (blk >> 2) & 255;
    const int b = blk >> 10;
    const int x0 = xseg * 64;

    // stage 3 rows x 66 px x 128 ch (bf16), zero-padded at borders
    const short* xin = X1 + (size_t)b * HW * 128;
    for (int i = tid; i < 198 * 16; i += 256) {
        int c16 = i & 15;
        int pix = i >> 4;
        int r = pix / 66, xx = pix % 66;
        int gy = yy + r - 1, gx = x0 + xx - 1;
        short8 v = {0, 0, 0, 0, 0, 0, 0, 0};
        if (gy >= 0 && gy < HT && gx >= 0 && gx < WD)
            v = *(const short8*)(xin + ((size_t)((gy << 8) + gx)) * 128 + c16 * 8);
        *(short8*)(&lds[(r * 66 + xx) * PADC1 + c16 * 8]) = v;
    }
    __syncthreads();

    f32x4 acc[4] = {{0,0,0,0},{0,0,0,0},{0,0,0,0},{0,0,0,0}};

    #pragma unroll 1
    for (int rs = 0; rs < 9; ++rs) {
        const int r = rs / 3, s = rs % 3;
        #pragma unroll
        for (int cc = 0; cc < 4; ++cc) {
            const int kc = rs * 4 + cc;
            short8 bfrag = *(const short8*)(wr + ((size_t)((kc * 4 + w) * 64 + l15 * 4 + q)) * 8);
            #pragma unroll
            for (int mt = 0; mt < 4; ++mt) {
                short8 afrag = *(const short8*)(&lds[(r * 66 + mt * 16 + l15 + s) * PADC1 + cc * 32 + q * 8]);
                acc[mt] = __builtin_amdgcn_mfma_f32_16x16x32_bf16(afrag, bfrag, acc[mt], 0, 0, 0);
            }
        }
    }

    // epilogue: ch = w*16 + l15 ; px = x0 + mt*16 + q*4 + reg ; NHWC bf16
    float bv = bias[w * 16 + l15];
    short* xo = X2 + (size_t)b * HW * 96;
    #pragma unroll
    for (int mt = 0; mt < 4; ++mt) {
        #pragma unroll
        for (int rg = 0; rg < 4; ++rg) {
            int px = x0 + mt * 16 + q * 4 + rg;
            float v = fmaxf(acc[mt][rg] + bv, 0.f);
            xo[((size_t)((yy << 8) + px)) * 96 + w * 16 + l15] = f2bf(v);
        }
    }
}

// ---------------------------------------------------------------------------
// om MFMA: X2 (NHWC bf16, 96ch incl flow+pad) -> omraw (B,216,HW) fp32.
// Block: 64px x 256ch(pad of 216); wave owns 4 n-tiles x 4 m-tiles.
// K = 27 chunks. Epilogue: LDS transpose -> coalesced NCHW f32 stores.
// ---------------------------------------------------------------------------
#define PADC2 104
__global__ __launch_bounds__(256) void om_mfma_kernel(
    const short* __restrict__ X2, const short* __restrict__ wr,
    const float* __restrict__ bias, float* __restrict__ omraw)
{
    __shared__ short lds[3 * 66 * PADC2];   // 41,184 B (>= 128*67*4 reuse)
    const int tid = threadIdx.x;
    const int w = __builtin_amdgcn_readfirstlane(tid >> 6);
    const int l15 = tid & 15;
    const int q = (tid >> 4) & 3;
    const int blk = blockIdx.x;
    const int xseg = blk & 3;
    const int yy = (blk >> 2) & 255;
    const int b = blk >> 10;
    const int x0 = xseg * 64;

    const short* xin = X2 + (size_t)b * HW * 96;
    for (int i = tid; i < 198 * 12; i += 256) {
        int pix = i / 12;
        int c8 = i - pix * 12;
        int r = pix / 66, xx = pix % 66;
        int gy = yy + r - 1, gx = x0 + xx - 1;
        short8 v = {0, 0, 0, 0, 0, 0, 0, 0};
        if (gy >= 0 && gy < HT && gx >= 0 && gx < WD)
            v = *(const short8*)(xin + ((size_t)((gy << 8) + gx)) * 96 + c8 * 8);
        *(short8*)(&lds[(r * 66 + xx) * PADC2 + c8 * 8]) = v;
    }
    __syncthreads();

    f32x4 acc[4][4];
    #pragma unroll
    for (int i = 0; i < 4; ++i)
        #pragma unroll
        for (int mt = 0; mt < 4; ++mt) acc[i][mt] = (f32x4){0,0,0,0};

    #pragma unroll 1
    for (int rs = 0; rs < 9; ++rs) {
        const int r = rs / 3, s = rs % 3;
        #pragma unroll
        for (int cc = 0; cc < 3; ++cc) {
            const int kc = rs * 3 + cc;
            short8 a[4];
            #pragma unroll
            for (int mt = 0; mt < 4; ++mt)
                a[mt] = *(const short8*)(&lds[(r * 66 + mt * 16 + l15 + s) * PADC2 + cc * 32 + q * 8]);
            #pragma unroll
            for (int i = 0; i < 4; ++i) {
                const int nt = w * 4 + i;
                short8 bfrag = *(const short8*)(wr + ((size_t)((kc * 16 + nt) * 64 + l15 * 4 + q)) * 8);
                #pragma unroll
                for (int mt = 0; mt < 4; ++mt)
                    acc[i][mt] = __builtin_amdgcn_mfma_f32_16x16x32_bf16(a[mt], bfrag, acc[i][mt], 0, 0, 0);
            }
        }
    }

    // epilogue: two passes of 128 channels through LDS transpose
    float* ldsT = (float*)lds;
    const int LT = 67;
    #pragma unroll 1
    for (int pass = 0; pass < 2; ++pass) {
        __syncthreads();
        if ((w >> 1) == pass) {
            int wl = w & 1;
            #pragma unroll
            for (int i = 0; i < 4; ++i) {
                int chl = (wl * 4 + i) * 16 + l15;   // 0..127
                #pragma unroll
                for (int mt = 0; mt < 4; ++mt)
                    #pragma unroll
                    for (int rg = 0; rg < 4; ++rg)
                        ldsT[chl * LT + mt * 16 + q * 4 + rg] = acc[i][mt][rg];
            }
        }
        __syncthreads();
        int chbase = pass * 128;
        for (int f = tid; f < 128 * 64; f += 256) {
            int chl = f >> 6, px = f & 63;
            int ch = chbase + chl;
            if (ch < 216) {
                float v = ldsT[chl * LT + px] + bias[ch];
                omraw[((size_t)b * 216 + ch) * HW + (yy << 8) + x0 + px] = v;
            }
        }
    }
}

// ---------------------------------------------------------------------------
// Repack dcn_w (o, ic=g*8+c, ky, kx) -> w2[g][k][c][o]
// ---------------------------------------------------------------------------
__global__ __launch_bounds__(256) void repack_dcn_kernel(
    const float* __restrict__ w, float* __restrict__ w2)
{
    int t = blockIdx.x * 256 + threadIdx.x;   // 36864 total
    int o = t & 63;
    int c = (t >> 6) & 7;
    int gk = t >> 9;          // 0..71
    int k = gk % 9;
    int g = gk / 9;
    w2[t] = w[(o * 64 + g * 8 + c) * 9 + k];
}

// ---------------------------------------------------------------------------
// dcn: deformable sampling + grouped einsum + bias. 1 thr/pixel.
// ---------------------------------------------------------------------------
__global__ __launch_bounds__(256) void dcn_kernel(
    const float* __restrict__ raw,    // (B,216,HW) om-conv output
    const float* __restrict__ flow,   // (B,2,HW)
    const float* __restrict__ nbr,    // (B,64,HW)
    const float* __restrict__ w2,     // [g][k][c][o]
    const float* __restrict__ bias,   // 64
    float* __restrict__ out)          // (B,64,HW)
{
    int t = blockIdx.x * 256 + threadIdx.x;
    int b = t >> 16;
    int pos = t & (HW - 1);
    int yy = pos >> 8, xx = pos & 255;

    const float* rawb = raw + (size_t)b * 216 * HW + pos;
    float fx = flow[b * 2 * HW + pos];
    float fy = flow[b * 2 * HW + HW + pos];
    const float* nb = nbr + (size_t)b * 64 * HW;

    float acc[64];
    #pragma unroll
    for (int o = 0; o < 64; ++o) acc[o] = bias[o];

    #pragma unroll 1
    for (int g = 0; g < 8; ++g) {
        const float* nbg = nb + g * 8 * HW;
        #pragma unroll 1
        for (int k = 0; k < 9; ++k) {
            float dy = rawb[(g * 18 + 2 * k) * HW] + fy;
            float dx = rawb[(g * 18 + 2 * k + 1) * HW] + fx;
            float mr = rawb[(144 + g * 9 + k) * HW];
            float m = 1.f / (1.f + __expf(-mr));

            float py = (float)(yy - 1 + k / 3) + dy;
            float px = (float)(xx - 1 + k % 3) + dx;
            Taps tp = make_taps(py, px);
            float w00 = tp.w00 * m, w01 = tp.w01 * m;
            float w10 = tp.w10 * m, w11 = tp.w11 * m;

            float s[8];
            #pragma unroll
            for (int c = 0; c < 8; ++c) {
                const float* pc = nbg + c * HW;
                s[c] = w00 * pc[tp.i00] + w01 * pc[tp.i01] +
                       w10 * pc[tp.i10] + w11 * pc[tp.i11];
            }

            const float* wp = w2 + (g * 9 + k) * 512;
            #pragma unroll
            for (int c = 0; c < 8; ++c) {
                float sc = s[c];
                #pragma unroll
                for (int o = 0; o < 64; ++o)
                    acc[o] = fmaf(sc, wp[c * 64 + o], acc[o]);
            }
        }
    }

    float* op = out + (size_t)b * 64 * HW + pos;
    #pragma unroll
    for (int o = 0; o < 64; ++o) op[o * HW] = acc[o];
}

// ---------------------------------------------------------------------------
extern "C" void kernel_launch(void* const* d_in, const int* in_sizes, int n_in,
                              void* d_out, int out_size, void* d_ws, size_t ws_size,
                              hipStream_t stream)
{
    const float* nbr  = (const float*)d_in[0];   // (2,64,256,256)
    const float* ref  = (const float*)d_in[1];   // (2,64,256,256)
    const float* flow = (const float*)d_in[2];   // (2,2,256,256)
    const float* c1w  = (const float*)d_in[3];   // (64,128,3,3)
    const float* c1b  = (const float*)d_in[4];   // (64)
    const float* omw  = (const float*)d_in[5];   // (216,66,3,3)
    const float* omb  = (const float*)d_in[6];   // (216)
    const float* dw   = (const float*)d_in[7];   // (64,64,3,3)
    const float* db   = (const float*)d_in[8];   // (64)
    float* out = (float*)d_out;

    char* wsb = (char*)d_ws;
    short* X1    = (short*)(wsb);                  // 33,554,432 B
    short* X2    = (short*)(wsb + 33554432);       // 25,165,824 B
    float* omraw = (float*)(wsb + 58720256);       // 113,246,208 B
    short* wr1   = (short*)(wsb + 171966464);      // 147,456 B
    short* wr2   = (short*)(wsb + 172113920);      // 442,368 B
    float* w2d   = (float*)(wsb + 172556288);      // 147,456 B

    repack_w1_kernel<<<288, 256, 0, stream>>>(c1w, wr1);
    repack_w2_kernel<<<864, 256, 0, stream>>>(omw, wr2);
    repack_dcn_kernel<<<144, 256, 0, stream>>>(dw, w2d);
    pack_x1_kernel<<<2048, 256, 0, stream>>>(nbr, ref, flow, X1);
    pack_x2_flow_kernel<<<512, 256, 0, stream>>>(flow, X2);
    conv1_mfma_kernel<<<2048, 256, 0, stream>>>(X1, c1b, wr1, X2);
    om_mfma_kernel<<<2048, 256, 0, stream>>>(X2, wr2, omb, omraw);
    dcn_kernel<<<512, 256, 0, stream>>>(omraw, flow, nbr, w2d, db, out);
}

// Round 4
// 615.194 us; speedup vs baseline: 3.4407x; 1.0519x over previous
//
#include <hip/hip_runtime.h>
#include <math.h>

#define HW 65536
#define WD 256
#define HT 256

typedef short short8 __attribute__((ext_vector_type(8)));
typedef float f32x4 __attribute__((ext_vector_type(4)));

__device__ __forceinline__ short f2bf(float f) {
    union { float f; unsigned u; } v; v.f = f;
    unsigned r = (v.u + 0x7fffu + ((v.u >> 16) & 1u)) >> 16;
    return (short)r;
}

__device__ __forceinline__ int iclamp(int v, int lo, int hi) {
    return v < lo ? lo : (v > hi ? hi : v);
}

struct Taps {
    int i00, i01, i10, i11;
    float w00, w01, w10, w11;
};

__device__ __forceinline__ Taps make_taps(float py, float px) {
    float fy0 = floorf(py), fx0 = floorf(px);
    float wy = py - fy0, wx = px - fx0;
    int y0 = (int)fy0, x0 = (int)fx0;
    int y1 = y0 + 1, x1 = x0 + 1;
    float vy0 = (y0 >= 0 && y0 <= HT - 1) ? 1.f : 0.f;
    float vy1 = (y1 >= 0 && y1 <= HT - 1) ? 1.f : 0.f;
    float vx0 = (x0 >= 0 && x0 <= WD - 1) ? 1.f : 0.f;
    float vx1 = (x1 >= 0 && x1 <= WD - 1) ? 1.f : 0.f;
    int yc0 = iclamp(y0, 0, HT - 1), yc1 = iclamp(y1, 0, HT - 1);
    int xc0 = iclamp(x0, 0, WD - 1), xc1 = iclamp(x1, 0, WD - 1);
    Taps t;
    t.i00 = yc0 * WD + xc0; t.i01 = yc0 * WD + xc1;
    t.i10 = yc1 * WD + xc0; t.i11 = yc1 * WD + xc1;
    t.w00 = (1.f - wy) * (1.f - wx) * vy0 * vx0;
    t.w01 = (1.f - wy) * wx * vy0 * vx1;
    t.w10 = wy * (1.f - wx) * vy1 * vx0;
    t.w11 = wy * wx * vy1 * vx1;
    return t;
}

// ---------------------------------------------------------------------------
// pack_x1: warp(nbr) + ref -> X1 (B,HW,128) NHWC bf16, via LDS transpose.
// ---------------------------------------------------------------------------
__global__ __launch_bounds__(256) void pack_x1_kernel(
    const float* __restrict__ nbr, const float* __restrict__ ref,
    const float* __restrict__ flow, short* __restrict__ X1)
{
    __shared__ short tile[64 * 130];
    int blk = blockIdx.x;              // b*1024 + grp
    int b = blk >> 10;
    int grp = blk & 1023;
    int px = threadIdx.x & 63;
    int qq = threadIdx.x >> 6;
    int pos = grp * 64 + px;
    int yy = pos >> 8, xx = pos & 255;

    float fx = flow[b * 2 * HW + pos];
    float fy = flow[b * 2 * HW + HW + pos];
    Taps tp = make_taps((float)yy + fy, (float)xx + fx);

    const float* nb = nbr + (size_t)b * 64 * HW;
    const float* rf = ref + (size_t)b * 64 * HW;
    #pragma unroll
    for (int j = 0; j < 16; ++j) {
        int c = qq * 16 + j;
        const float* pc = nb + c * HW;
        float v = tp.w00 * pc[tp.i00] + tp.w01 * pc[tp.i01] +
                  tp.w10 * pc[tp.i10] + tp.w11 * pc[tp.i11];
        tile[px * 130 + c] = f2bf(v);
        tile[px * 130 + 64 + c] = f2bf(rf[c * HW + pos]);
    }
    __syncthreads();

    short* xo = X1 + ((size_t)b * HW + grp * 64) * 128;
    #pragma unroll
    for (int f8 = threadIdx.x; f8 < 1024; f8 += 256) {
        int p = (f8 * 8) >> 7;
        int c = (f8 * 8) & 127;
        short8 v;
        #pragma unroll
        for (int j = 0; j < 8; ++j) v[j] = tile[p * 130 + c + j];
        *(short8*)(xo + f8 * 8) = v;
    }
}

// ---------------------------------------------------------------------------
// pack_x2_flow: fill X2 channels 64..95 (flow bf16 + zero pad).
// ---------------------------------------------------------------------------
__global__ __launch_bounds__(256) void pack_x2_flow_kernel(
    const float* __restrict__ flow, short* __restrict__ X2)
{
    int t = blockIdx.x * 256 + threadIdx.x;   // 2*HW
    int b = t >> 16;
    int pos = t & (HW - 1);
    short bx = f2bf(flow[b * 2 * HW + pos]);
    short by = f2bf(flow[b * 2 * HW + HW + pos]);
    short* p = X2 + ((size_t)b * HW + pos) * 96 + 64;
    short8 first = {bx, by, 0, 0, 0, 0, 0, 0};
    short8 z = {0, 0, 0, 0, 0, 0, 0, 0};
    *(short8*)(p) = first;
    *(short8*)(p + 8) = z;
    *(short8*)(p + 16) = z;
    *(short8*)(p + 24) = z;
}

// ---------------------------------------------------------------------------
// Weight repacks to MFMA B-fragment order.
// ---------------------------------------------------------------------------
__global__ __launch_bounds__(256) void repack_w1_kernel(
    const float* __restrict__ w, short* __restrict__ wr)
{
    int t = blockIdx.x * 256 + threadIdx.x;  // 73728
    int j = t & 7, q = (t >> 3) & 3, l = (t >> 5) & 15;
    int nt = (t >> 9) & 3, kc = t >> 11;
    int k = kc * 32 + q * 8 + j;
    int rs = k >> 7, c = k & 127;
    int n = nt * 16 + l;
    wr[t] = f2bf(w[(n * 128 + c) * 9 + rs]);
}

__global__ __launch_bounds__(256) void repack_w2_kernel(
    const float* __restrict__ w, short* __restrict__ wr)
{
    int t = blockIdx.x * 256 + threadIdx.x;  // 221184
    int j = t & 7, q = (t >> 3) & 3, l = (t >> 5) & 15;
    int nt = (t >> 9) & 15, kc = t >> 13;
    int k = kc * 32 + q * 8 + j;
    int rs = k / 96, c = k % 96;
    int n = nt * 16 + l;
    float v = (n < 216 && c < 66) ? w[(n * 66 + c) * 9 + rs] : 0.f;
    wr[t] = f2bf(v);
}

// dcn weights -> B-frag order: flat = (((g*3+kc)*4+nt)*64 + l15*4+q)*8 + j
// Kidx = kc*32 + q*8 + j ; k = Kidx>>3, c = Kidx&7 (pad k=9..11 -> 0)
__global__ __launch_bounds__(256) void repack_dcn_kernel(
    const float* __restrict__ w, short* __restrict__ wr)
{
    int t = blockIdx.x * 256 + threadIdx.x;   // 49152
    int j = t & 7, q = (t >> 3) & 3, l = (t >> 5) & 15;
    int rem = t >> 9;           // (g*3+kc)*4 + nt
    int nt = rem & 3;
    int gkc = rem >> 2;         // g*3 + kc
    int kc = gkc % 3, g = gkc / 3;
    int Kidx = kc * 32 + q * 8 + j;
    int k = Kidx >> 3, c = Kidx & 7;
    int och = nt * 16 + l;
    float v = (k < 9) ? w[(och * 64 + g * 8 + c) * 9 + k] : 0.f;
    wr[t] = f2bf(v);
}

// ---------------------------------------------------------------------------
// conv1 MFMA: X1 (NHWC bf16, 128ch) -> fea ch 0..63 of X2 (NHWC bf16, 96).
// ---------------------------------------------------------------------------
#define PADC1 136
__global__ __launch_bounds__(256) void conv1_mfma_kernel(
    const short* __restrict__ X1, const float* __restrict__ bias,
    const short* __restrict__ wr, short* __restrict__ X2)
{
    __shared__ short lds[3 * 66 * PADC1];
    const int tid = threadIdx.x;
    const int w = __builtin_amdgcn_readfirstlane(tid >> 6);
    const int l15 = tid & 15;
    const int q = (tid >> 4) & 3;
    const int blk = blockIdx.x;
    const int xseg = blk & 3;
    const int yy = (blk >> 2) & 255;
    const int b = blk >> 10;
    const int x0 = xseg * 64;

    const short* xin = X1 + (size_t)b * HW * 128;
    for (int i = tid; i < 198 * 16; i += 256) {
        int c16 = i & 15;
        int pix = i >> 4;
        int r = pix / 66, xx = pix % 66;
        int gy = yy + r - 1, gx = x0 + xx - 1;
        short8 v = {0, 0, 0, 0, 0, 0, 0, 0};
        if (gy >= 0 && gy < HT && gx >= 0 && gx < WD)
            v = *(const short8*)(xin + ((size_t)((gy << 8) + gx)) * 128 + c16 * 8);
        *(short8*)(&lds[(r * 66 + xx) * PADC1 + c16 * 8]) = v;
    }
    __syncthreads();

    f32x4 acc[4] = {{0,0,0,0},{0,0,0,0},{0,0,0,0},{0,0,0,0}};

    #pragma unroll 1
    for (int rs = 0; rs < 9; ++rs) {
        const int r = rs / 3, s = rs % 3;
        #pragma unroll
        for (int cc = 0; cc < 4; ++cc) {
            const int kc = rs * 4 + cc;
            short8 bfrag = *(const short8*)(wr + ((size_t)((kc * 4 + w) * 64 + l15 * 4 + q)) * 8);
            #pragma unroll
            for (int mt = 0; mt < 4; ++mt) {
                short8 afrag = *(const short8*)(&lds[(r * 66 + mt * 16 + l15 + s) * PADC1 + cc * 32 + q * 8]);
                acc[mt] = __builtin_amdgcn_mfma_f32_16x16x32_bf16(afrag, bfrag, acc[mt], 0, 0, 0);
            }
        }
    }

    float bv = bias[w * 16 + l15];
    short* xo = X2 + (size_t)b * HW * 96;
    #pragma unroll
    for (int mt = 0; mt < 4; ++mt) {
        #pragma unroll
        for (int rg = 0; rg < 4; ++rg) {
            int px = x0 + mt * 16 + q * 4 + rg;
            float v = fmaxf(acc[mt][rg] + bv, 0.f);
            xo[((size_t)((yy << 8) + px)) * 96 + w * 16 + l15] = f2bf(v);
        }
    }
}

// ---------------------------------------------------------------------------
// om MFMA: X2 (NHWC bf16, 96ch) -> omraw (B,216,HW) fp32.
// ---------------------------------------------------------------------------
#define PADC2 104
__global__ __launch_bounds__(256) void om_mfma_kernel(
    const short* __restrict__ X2, const short* __restrict__ wr,
    const float* __restrict__ bias, float* __restrict__ omraw)
{
    __shared__ short lds[3 * 66 * PADC2];
    const int tid = threadIdx.x;
    const int w = __builtin_amdgcn_readfirstlane(tid >> 6);
    const int l15 = tid & 15;
    const int q = (tid >> 4) & 3;
    const int blk = blockIdx.x;
    const int xseg = blk & 3;
    const int yy = (blk >> 2) & 255;
    const int b = blk >> 10;
    const int x0 = xseg * 64;

    const short* xin = X2 + (size_t)b * HW * 96;
    for (int i = tid; i < 198 * 12; i += 256) {
        int pix = i / 12;
        int c8 = i - pix * 12;
        int r = pix / 66, xx = pix % 66;
        int gy = yy + r - 1, gx = x0 + xx - 1;
        short8 v = {0, 0, 0, 0, 0, 0, 0, 0};
        if (gy >= 0 && gy < HT && gx >= 0 && gx < WD)
            v = *(const short8*)(xin + ((size_t)((gy << 8) + gx)) * 96 + c8 * 8);
        *(short8*)(&lds[(r * 66 + xx) * PADC2 + c8 * 8]) = v;
    }
    __syncthreads();

    f32x4 acc[4][4];
    #pragma unroll
    for (int i = 0; i < 4; ++i)
        #pragma unroll
        for (int mt = 0; mt < 4; ++mt) acc[i][mt] = (f32x4){0,0,0,0};

    #pragma unroll 1
    for (int rs = 0; rs < 9; ++rs) {
        const int r = rs / 3, s = rs % 3;
        #pragma unroll
        for (int cc = 0; cc < 3; ++cc) {
            const int kc = rs * 3 + cc;
            short8 a[4];
            #pragma unroll
            for (int mt = 0; mt < 4; ++mt)
                a[mt] = *(const short8*)(&lds[(r * 66 + mt * 16 + l15 + s) * PADC2 + cc * 32 + q * 8]);
            #pragma unroll
            for (int i = 0; i < 4; ++i) {
                const int nt = w * 4 + i;
                short8 bfrag = *(const short8*)(wr + ((size_t)((kc * 16 + nt) * 64 + l15 * 4 + q)) * 8);
                #pragma unroll
                for (int mt = 0; mt < 4; ++mt)
                    acc[i][mt] = __builtin_amdgcn_mfma_f32_16x16x32_bf16(a[mt], bfrag, acc[i][mt], 0, 0, 0);
            }
        }
    }

    float* ldsT = (float*)lds;
    const int LT = 67;
    #pragma unroll 1
    for (int pass = 0; pass < 2; ++pass) {
        __syncthreads();
        if ((w >> 1) == pass) {
            int wl = w & 1;
            #pragma unroll
            for (int i = 0; i < 4; ++i) {
                int chl = (wl * 4 + i) * 16 + l15;
                #pragma unroll
                for (int mt = 0; mt < 4; ++mt)
                    #pragma unroll
                    for (int rg = 0; rg < 4; ++rg)
                        ldsT[chl * LT + mt * 16 + q * 4 + rg] = acc[i][mt][rg];
            }
        }
        __syncthreads();
        int chbase = pass * 128;
        for (int f = tid; f < 128 * 64; f += 256) {
            int chl = f >> 6, px = f & 63;
            int ch = chbase + chl;
            if (ch < 216) {
                float v = ldsT[chl * LT + px] + bias[ch];
                omraw[((size_t)b * 216 + ch) * HW + (yy << 8) + x0 + px] = v;
            }
        }
    }
}

// ---------------------------------------------------------------------------
// dcn MFMA: sampled A-tile (64 px x 96 K per group) built in LDS as bf16,
// B = repacked dcn weights; acc = 4 x f32x4 (16 VGPR) -> no spill.
// K order within group: Kidx = k*8 + c (k = tap, c = channel-in-group).
// ---------------------------------------------------------------------------
__global__ __launch_bounds__(256) void dcn_mfma_kernel(
    const float* __restrict__ raw,    // (B,216,HW)
    const float* __restrict__ flow,   // (B,2,HW)
    const float* __restrict__ nbr,    // (B,64,HW)
    const short* __restrict__ wrd,    // B-frag order, 49152
    const float* __restrict__ bias,   // 64
    float* __restrict__ out)          // (B,64,HW)
{
    __shared__ __align__(16) char ldsraw[16640];
    short* ldsA = (short*)ldsraw;     // [64 px][104] (96 used)
    float* ldsT = (float*)ldsraw;     // [64 och][65] epilogue reuse

    const int tid = threadIdx.x;
    const int w = __builtin_amdgcn_readfirstlane(tid >> 6);
    const int l15 = tid & 15;
    const int q = (tid >> 4) & 3;
    const int qq = tid >> 6;
    const int px = tid & 63;

    const int blk = blockIdx.x;
    const int b = blk >> 10;
    const int grp = blk & 1023;
    const int pos0 = grp * 64;
    const int pos = pos0 + px;
    const int yy = pos >> 8, xx = pos & 255;

    const float* rawb = raw + (size_t)b * 216 * HW + pos;
    const float fx = flow[b * 2 * HW + pos];
    const float fy = flow[b * 2 * HW + HW + pos];
    const float* nb = nbr + (size_t)b * 64 * HW;

    f32x4 acc[4] = {{0,0,0,0},{0,0,0,0},{0,0,0,0},{0,0,0,0}};

    #pragma unroll 1
    for (int g = 0; g < 8; ++g) {
        __syncthreads();   // protect ldsA from previous iteration's reads
        const float* nbg = nb + g * 8 * HW;
        // fill phase: thread handles taps k = qq, qq+4, qq+8 (k>=9 -> zeros)
        #pragma unroll
        for (int it = 0; it < 3; ++it) {
            int k = qq + 4 * it;
            short8 v = {0, 0, 0, 0, 0, 0, 0, 0};
            if (k < 9) {
                float dy = rawb[(g * 18 + 2 * k) * HW] + fy;
                float dx = rawb[(g * 18 + 2 * k + 1) * HW] + fx;
                float mr = rawb[(144 + g * 9 + k) * HW];
                float m = 1.f / (1.f + __expf(-mr));
                float py = (float)(yy - 1 + k / 3) + dy;
                float pxx = (float)(xx - 1 + k % 3) + dx;
                Taps tp = make_taps(py, pxx);
                float w00 = tp.w00 * m, w01 = tp.w01 * m;
                float w10 = tp.w10 * m, w11 = tp.w11 * m;
                #pragma unroll
                for (int c = 0; c < 8; ++c) {
                    const float* pc = nbg + c * HW;
                    float s = w00 * pc[tp.i00] + w01 * pc[tp.i01] +
                              w10 * pc[tp.i10] + w11 * pc[tp.i11];
                    v[c] = f2bf(s);
                }
            }
            *(short8*)(&ldsA[px * 104 + k * 8]) = v;
        }
        __syncthreads();
        // MFMA phase: K = 96 (3 chunks), wave w owns och-tile w
        #pragma unroll
        for (int kc = 0; kc < 3; ++kc) {
            short8 bfrag = *(const short8*)(wrd +
                ((size_t)(((g * 3 + kc) * 4 + w) * 64 + l15 * 4 + q)) * 8);
            #pragma unroll
            for (int mt = 0; mt < 4; ++mt) {
                short8 a = *(const short8*)(&ldsA[(mt * 16 + l15) * 104 + kc * 32 + q * 8]);
                acc[mt] = __builtin_amdgcn_mfma_f32_16x16x32_bf16(a, bfrag, acc[mt], 0, 0, 0);
            }
        }
    }

    // epilogue: LDS transpose -> coalesced NCHW stores (+bias)
    __syncthreads();
    #pragma unroll
    for (int mt = 0; mt < 4; ++mt)
        #pragma unroll
        for (int rg = 0; rg < 4; ++rg)
            ldsT[(w * 16 + l15) * 65 + mt * 16 + q * 4 + rg] = acc[mt][rg];
    __syncthreads();
    float* ob = out + (size_t)b * 64 * HW + pos0;
    for (int f = tid; f < 4096; f += 256) {
        int och = f >> 6, p2 = f & 63;
        ob[(size_t)och * HW + p2] = ldsT[och * 65 + p2] + bias[och];
    }
}

// ---------------------------------------------------------------------------
extern "C" void kernel_launch(void* const* d_in, const int* in_sizes, int n_in,
                              void* d_out, int out_size, void* d_ws, size_t ws_size,
                              hipStream_t stream)
{
    const float* nbr  = (const float*)d_in[0];
    const float* ref  = (const float*)d_in[1];
    const float* flow = (const float*)d_in[2];
    const float* c1w  = (const float*)d_in[3];
    const float* c1b  = (const float*)d_in[4];
    const float* omw  = (const float*)d_in[5];
    const float* omb  = (const float*)d_in[6];
    const float* dw   = (const float*)d_in[7];
    const float* db   = (const float*)d_in[8];
    float* out = (float*)d_out;

    char* wsb = (char*)d_ws;
    short* X1    = (short*)(wsb);                  // 33,554,432 B
    short* X2    = (short*)(wsb + 33554432);       // 25,165,824 B
    float* omraw = (float*)(wsb + 58720256);       // 113,246,208 B
    short* wr1   = (short*)(wsb + 171966464);      // 147,456 B
    short* wr2   = (short*)(wsb + 172113920);      // 442,368 B
    short* wrd   = (short*)(wsb + 172556288);      // 98,304 B

    repack_w1_kernel<<<288, 256, 0, stream>>>(c1w, wr1);
    repack_w2_kernel<<<864, 256, 0, stream>>>(omw, wr2);
    repack_dcn_kernel<<<192, 256, 0, stream>>>(dw, wrd);
    pack_x1_kernel<<<2048, 256, 0, stream>>>(nbr, ref, flow, X1);
    pack_x2_flow_kernel<<<512, 256, 0, stream>>>(flow, X2);
    conv1_mfma_kernel<<<2048, 256, 0, stream>>>(X1, c1b, wr1, X2);
    om_mfma_kernel<<<2048, 256, 0, stream>>>(X2, wr2, omb, omraw);
    dcn_mfma_kernel<<<2048, 256, 0, stream>>>(omraw, flow, nbr, wrd, db, out);
}

// Round 5
// 493.355 us; speedup vs baseline: 4.2905x; 1.2470x over previous
//
#include <hip/hip_runtime.h>
#include <math.h>

#define HW 65536
#define WD 256
#define HT 256

typedef short short8 __attribute__((ext_vector_type(8)));
typedef float f32x4 __attribute__((ext_vector_type(4)));

__device__ __forceinline__ short f2bf(float f) {
    union { float f; unsigned u; } v; v.f = f;
    unsigned r = (v.u + 0x7fffu + ((v.u >> 16) & 1u)) >> 16;
    return (short)r;
}

__device__ __forceinline__ float bf2f(short s) {
    union { unsigned u; float f; } v;
    v.u = ((unsigned)(unsigned short)s) << 16;
    return v.f;
}

__device__ __forceinline__ int iclamp(int v, int lo, int hi) {
    return v < lo ? lo : (v > hi ? hi : v);
}

struct Taps {
    int i00, i01, i10, i11;
    float w00, w01, w10, w11;
};

__device__ __forceinline__ Taps make_taps(float py, float px) {
    float fy0 = floorf(py), fx0 = floorf(px);
    float wy = py - fy0, wx = px - fx0;
    int y0 = (int)fy0, x0 = (int)fx0;
    int y1 = y0 + 1, x1 = x0 + 1;
    float vy0 = (y0 >= 0 && y0 <= HT - 1) ? 1.f : 0.f;
    float vy1 = (y1 >= 0 && y1 <= HT - 1) ? 1.f : 0.f;
    float vx0 = (x0 >= 0 && x0 <= WD - 1) ? 1.f : 0.f;
    float vx1 = (x1 >= 0 && x1 <= WD - 1) ? 1.f : 0.f;
    int yc0 = iclamp(y0, 0, HT - 1), yc1 = iclamp(y1, 0, HT - 1);
    int xc0 = iclamp(x0, 0, WD - 1), xc1 = iclamp(x1, 0, WD - 1);
    Taps t;
    t.i00 = yc0 * WD + xc0; t.i01 = yc0 * WD + xc1;
    t.i10 = yc1 * WD + xc0; t.i11 = yc1 * WD + xc1;
    t.w00 = (1.f - wy) * (1.f - wx) * vy0 * vx0;
    t.w01 = (1.f - wy) * wx * vy0 * vx1;
    t.w10 = wy * (1.f - wx) * vy1 * vx0;
    t.w11 = wy * wx * vy1 * vx1;
    return t;
}

// ---------------------------------------------------------------------------
// pack_x1: warp(nbr) + ref -> X1 (B,HW,128) NHWC bf16, via LDS transpose.
// ---------------------------------------------------------------------------
__global__ __launch_bounds__(256) void pack_x1_kernel(
    const float* __restrict__ nbr, const float* __restrict__ ref,
    const float* __restrict__ flow, short* __restrict__ X1)
{
    __shared__ short tile[64 * 130];
    int blk = blockIdx.x;              // b*1024 + grp
    int b = blk >> 10;
    int grp = blk & 1023;
    int px = threadIdx.x & 63;
    int qq = threadIdx.x >> 6;
    int pos = grp * 64 + px;
    int yy = pos >> 8, xx = pos & 255;

    float fx = flow[b * 2 * HW + pos];
    float fy = flow[b * 2 * HW + HW + pos];
    Taps tp = make_taps((float)yy + fy, (float)xx + fx);

    const float* nb = nbr + (size_t)b * 64 * HW;
    const float* rf = ref + (size_t)b * 64 * HW;
    #pragma unroll
    for (int j = 0; j < 16; ++j) {
        int c = qq * 16 + j;
        const float* pc = nb + c * HW;
        float v = tp.w00 * pc[tp.i00] + tp.w01 * pc[tp.i01] +
                  tp.w10 * pc[tp.i10] + tp.w11 * pc[tp.i11];
        tile[px * 130 + c] = f2bf(v);
        tile[px * 130 + 64 + c] = f2bf(rf[c * HW + pos]);
    }
    __syncthreads();

    short* xo = X1 + ((size_t)b * HW + grp * 64) * 128;
    #pragma unroll
    for (int f8 = threadIdx.x; f8 < 1024; f8 += 256) {
        int p = (f8 * 8) >> 7;
        int c = (f8 * 8) & 127;
        short8 v;
        #pragma unroll
        for (int j = 0; j < 8; ++j) v[j] = tile[p * 130 + c + j];
        *(short8*)(xo + f8 * 8) = v;
    }
}

// ---------------------------------------------------------------------------
// pack_nbr: nbr (B,64,HW) f32 -> N2 (B,HW,64) bf16 via LDS transpose.
// ---------------------------------------------------------------------------
__global__ __launch_bounds__(256) void pack_nbr_kernel(
    const float* __restrict__ nbr, short* __restrict__ N2)
{
    __shared__ short tile[64 * 66];
    int blk = blockIdx.x;              // b*1024 + grp
    int b = blk >> 10;
    int grp = blk & 1023;
    int px = threadIdx.x & 63;
    int qq = threadIdx.x >> 6;
    int pos = grp * 64 + px;

    const float* nb = nbr + (size_t)b * 64 * HW;
    #pragma unroll
    for (int j = 0; j < 16; ++j) {
        int c = qq * 16 + j;
        tile[px * 66 + c] = f2bf(nb[c * HW + pos]);
    }
    __syncthreads();

    short* xo = N2 + ((size_t)b * HW + grp * 64) * 64;
    #pragma unroll
    for (int f8 = threadIdx.x; f8 < 512; f8 += 256) {
        int p = f8 >> 3;
        int c = (f8 & 7) * 8;
        short8 v;
        #pragma unroll
        for (int j = 0; j < 8; ++j) v[j] = tile[p * 66 + c + j];
        *(short8*)(xo + f8 * 8) = v;
    }
}

// ---------------------------------------------------------------------------
// pack_x2_flow: fill X2 channels 64..95 (flow bf16 + zero pad).
// ---------------------------------------------------------------------------
__global__ __launch_bounds__(256) void pack_x2_flow_kernel(
    const float* __restrict__ flow, short* __restrict__ X2)
{
    int t = blockIdx.x * 256 + threadIdx.x;   // 2*HW
    int b = t >> 16;
    int pos = t & (HW - 1);
    short bx = f2bf(flow[b * 2 * HW + pos]);
    short by = f2bf(flow[b * 2 * HW + HW + pos]);
    short* p = X2 + ((size_t)b * HW + pos) * 96 + 64;
    short8 first = {bx, by, 0, 0, 0, 0, 0, 0};
    short8 z = {0, 0, 0, 0, 0, 0, 0, 0};
    *(short8*)(p) = first;
    *(short8*)(p + 8) = z;
    *(short8*)(p + 16) = z;
    *(short8*)(p + 24) = z;
}

// ---------------------------------------------------------------------------
// Weight repacks to MFMA B-fragment order.
// ---------------------------------------------------------------------------
__global__ __launch_bounds__(256) void repack_w1_kernel(
    const float* __restrict__ w, short* __restrict__ wr)
{
    int t = blockIdx.x * 256 + threadIdx.x;  // 73728
    int j = t & 7, q = (t >> 3) & 3, l = (t >> 5) & 15;
    int nt = (t >> 9) & 3, kc = t >> 11;
    int k = kc * 32 + q * 8 + j;
    int rs = k >> 7, c = k & 127;
    int n = nt * 16 + l;
    wr[t] = f2bf(w[(n * 128 + c) * 9 + rs]);
}

__global__ __launch_bounds__(256) void repack_w2_kernel(
    const float* __restrict__ w, short* __restrict__ wr)
{
    int t = blockIdx.x * 256 + threadIdx.x;  // 221184
    int j = t & 7, q = (t >> 3) & 3, l = (t >> 5) & 15;
    int nt = (t >> 9) & 15, kc = t >> 13;
    int k = kc * 32 + q * 8 + j;
    int rs = k / 96, c = k % 96;
    int n = nt * 16 + l;
    float v = (n < 216 && c < 66) ? w[(n * 66 + c) * 9 + rs] : 0.f;
    wr[t] = f2bf(v);
}

// dcn weights -> B-frag order: flat = (((g*3+kc)*4+nt)*64 + l15*4+q)*8 + j
__global__ __launch_bounds__(256) void repack_dcn_kernel(
    const float* __restrict__ w, short* __restrict__ wr)
{
    int t = blockIdx.x * 256 + threadIdx.x;   // 49152
    int j = t & 7, q = (t >> 3) & 3, l = (t >> 5) & 15;
    int rem = t >> 9;           // (g*3+kc)*4 + nt
    int nt = rem & 3;
    int gkc = rem >> 2;         // g*3 + kc
    int kc = gkc % 3, g = gkc / 3;
    int Kidx = kc * 32 + q * 8 + j;
    int k = Kidx >> 3, c = Kidx & 7;
    int och = nt * 16 + l;
    float v = (k < 9) ? w[(och * 64 + g * 8 + c) * 9 + k] : 0.f;
    wr[t] = f2bf(v);
}

// ---------------------------------------------------------------------------
// conv1 MFMA: X1 (NHWC bf16, 128ch) -> fea ch 0..63 of X2 (NHWC bf16, 96).
// ---------------------------------------------------------------------------
#define PADC1 136
__global__ __launch_bounds__(256) void conv1_mfma_kernel(
    const short* __restrict__ X1, const float* __restrict__ bias,
    const short* __restrict__ wr, short* __restrict__ X2)
{
    __shared__ short lds[3 * 66 * PADC1];
    const int tid = threadIdx.x;
    const int w = __builtin_amdgcn_readfirstlane(tid >> 6);
    const int l15 = tid & 15;
    const int q = (tid >> 4) & 3;
    const int blk = blockIdx.x;
    const int xseg = blk & 3;
    const int yy = (blk >> 2) & 255;
    const int b = blk >> 10;
    const int x0 = xseg * 64;

    const short* xin = X1 + (size_t)b * HW * 128;
    for (int i = tid; i < 198 * 16; i += 256) {
        int c16 = i & 15;
        int pix = i >> 4;
        int r = pix / 66, xx = pix % 66;
        int gy = yy + r - 1, gx = x0 + xx - 1;
        short8 v = {0, 0, 0, 0, 0, 0, 0, 0};
        if (gy >= 0 && gy < HT && gx >= 0 && gx < WD)
            v = *(const short8*)(xin + ((size_t)((gy << 8) + gx)) * 128 + c16 * 8);
        *(short8*)(&lds[(r * 66 + xx) * PADC1 + c16 * 8]) = v;
    }
    __syncthreads();

    f32x4 acc[4] = {{0,0,0,0},{0,0,0,0},{0,0,0,0},{0,0,0,0}};

    #pragma unroll 1
    for (int rs = 0; rs < 9; ++rs) {
        const int r = rs / 3, s = rs % 3;
        #pragma unroll
        for (int cc = 0; cc < 4; ++cc) {
            const int kc = rs * 4 + cc;
            short8 bfrag = *(const short8*)(wr + ((size_t)((kc * 4 + w) * 64 + l15 * 4 + q)) * 8);
            #pragma unroll
            for (int mt = 0; mt < 4; ++mt) {
                short8 afrag = *(const short8*)(&lds[(r * 66 + mt * 16 + l15 + s) * PADC1 + cc * 32 + q * 8]);
                acc[mt] = __builtin_amdgcn_mfma_f32_16x16x32_bf16(afrag, bfrag, acc[mt], 0, 0, 0);
            }
        }
    }

    float bv = bias[w * 16 + l15];
    short* xo = X2 + (size_t)b * HW * 96;
    #pragma unroll
    for (int mt = 0; mt < 4; ++mt) {
        #pragma unroll
        for (int rg = 0; rg < 4; ++rg) {
            int px = x0 + mt * 16 + q * 4 + rg;
            float v = fmaxf(acc[mt][rg] + bv, 0.f);
            xo[((size_t)((yy << 8) + px)) * 96 + w * 16 + l15] = f2bf(v);
        }
    }
}

// ---------------------------------------------------------------------------
// om MFMA: X2 (NHWC bf16, 96ch) -> omraw (B,216,HW) fp32.
// ---------------------------------------------------------------------------
#define PADC2 104
__global__ __launch_bounds__(256) void om_mfma_kernel(
    const short* __restrict__ X2, const short* __restrict__ wr,
    const float* __restrict__ bias, float* __restrict__ omraw)
{
    __shared__ short lds[3 * 66 * PADC2];
    const int tid = threadIdx.x;
    const int w = __builtin_amdgcn_readfirstlane(tid >> 6);
    const int l15 = tid & 15;
    const int q = (tid >> 4) & 3;
    const int blk = blockIdx.x;
    const int xseg = blk & 3;
    const int yy = (blk >> 2) & 255;
    const int b = blk >> 10;
    const int x0 = xseg * 64;

    const short* xin = X2 + (size_t)b * HW * 96;
    for (int i = tid; i < 198 * 12; i += 256) {
        int pix = i / 12;
        int c8 = i - pix * 12;
        int r = pix / 66, xx = pix % 66;
        int gy = yy + r - 1, gx = x0 + xx - 1;
        short8 v = {0, 0, 0, 0, 0, 0, 0, 0};
        if (gy >= 0 && gy < HT && gx >= 0 && gx < WD)
            v = *(const short8*)(xin + ((size_t)((gy << 8) + gx)) * 96 + c8 * 8);
        *(short8*)(&lds[(r * 66 + xx) * PADC2 + c8 * 8]) = v;
    }
    __syncthreads();

    f32x4 acc[4][4];
    #pragma unroll
    for (int i = 0; i < 4; ++i)
        #pragma unroll
        for (int mt = 0; mt < 4; ++mt) acc[i][mt] = (f32x4){0,0,0,0};

    #pragma unroll 1
    for (int rs = 0; rs < 9; ++rs) {
        const int r = rs / 3, s = rs % 3;
        #pragma unroll
        for (int cc = 0; cc < 3; ++cc) {
            const int kc = rs * 3 + cc;
            short8 a[4];
            #pragma unroll
            for (int mt = 0; mt < 4; ++mt)
                a[mt] = *(const short8*)(&lds[(r * 66 + mt * 16 + l15 + s) * PADC2 + cc * 32 + q * 8]);
            #pragma unroll
            for (int i = 0; i < 4; ++i) {
                const int nt = w * 4 + i;
                short8 bfrag = *(const short8*)(wr + ((size_t)((kc * 16 + nt) * 64 + l15 * 4 + q)) * 8);
                #pragma unroll
                for (int mt = 0; mt < 4; ++mt)
                    acc[i][mt] = __builtin_amdgcn_mfma_f32_16x16x32_bf16(a[mt], bfrag, acc[i][mt], 0, 0, 0);
            }
        }
    }

    float* ldsT = (float*)lds;
    const int LT = 67;
    #pragma unroll 1
    for (int pass = 0; pass < 2; ++pass) {
        __syncthreads();
        if ((w >> 1) == pass) {
            int wl = w & 1;
            #pragma unroll
            for (int i = 0; i < 4; ++i) {
                int chl = (wl * 4 + i) * 16 + l15;
                #pragma unroll
                for (int mt = 0; mt < 4; ++mt)
                    #pragma unroll
                    for (int rg = 0; rg < 4; ++rg)
                        ldsT[chl * LT + mt * 16 + q * 4 + rg] = acc[i][mt][rg];
            }
        }
        __syncthreads();
        int chbase = pass * 128;
        for (int f = tid; f < 128 * 64; f += 256) {
            int chl = f >> 6, px = f & 63;
            int ch = chbase + chl;
            if (ch < 216) {
                float v = ldsT[chl * LT + px] + bias[ch];
                omraw[((size_t)b * 216 + ch) * HW + (yy << 8) + x0 + px] = v;
            }
        }
    }
}

// ---------------------------------------------------------------------------
// dcn MFMA: sampled A-tile (64 px x 96 K per group) built in LDS as bf16.
// Gathers now read N2 (NHWC bf16): one 16B load covers all 8 group channels.
// ---------------------------------------------------------------------------
__global__ __launch_bounds__(256) void dcn_mfma_kernel(
    const float* __restrict__ raw,    // (B,216,HW)
    const float* __restrict__ flow,   // (B,2,HW)
    const short* __restrict__ N2,     // (B,HW,64) bf16
    const short* __restrict__ wrd,    // B-frag order, 49152
    const float* __restrict__ bias,   // 64
    float* __restrict__ out)          // (B,64,HW)
{
    __shared__ __align__(16) char ldsraw[16640];
    short* ldsA = (short*)ldsraw;     // [64 px][104] (96 used)
    float* ldsT = (float*)ldsraw;     // [64 och][65] epilogue reuse

    const int tid = threadIdx.x;
    const int w = __builtin_amdgcn_readfirstlane(tid >> 6);
    const int l15 = tid & 15;
    const int q = (tid >> 4) & 3;
    const int qq = tid >> 6;
    const int px = tid & 63;

    const int blk = blockIdx.x;
    const int b = blk >> 10;
    const int grp = blk & 1023;
    const int pos0 = grp * 64;
    const int pos = pos0 + px;
    const int yy = pos >> 8, xx = pos & 255;

    const float* rawb = raw + (size_t)b * 216 * HW + pos;
    const float fx = flow[b * 2 * HW + pos];
    const float fy = flow[b * 2 * HW + HW + pos];
    const short* nb2 = N2 + (size_t)b * HW * 64;

    f32x4 acc[4] = {{0,0,0,0},{0,0,0,0},{0,0,0,0},{0,0,0,0}};

    #pragma unroll 1
    for (int g = 0; g < 8; ++g) {
        __syncthreads();   // protect ldsA from previous iteration's reads
        // fill phase: thread handles taps k = qq, qq+4, qq+8 (k>=9 -> zeros)
        #pragma unroll
        for (int it = 0; it < 3; ++it) {
            int k = qq + 4 * it;
            short8 v = {0, 0, 0, 0, 0, 0, 0, 0};
            if (k < 9) {
                float dy = rawb[(g * 18 + 2 * k) * HW] + fy;
                float dx = rawb[(g * 18 + 2 * k + 1) * HW] + fx;
                float mr = rawb[(144 + g * 9 + k) * HW];
                float m = 1.f / (1.f + __expf(-mr));
                float py = (float)(yy - 1 + k / 3) + dy;
                float pxx = (float)(xx - 1 + k % 3) + dx;
                Taps tp = make_taps(py, pxx);
                float w00 = tp.w00 * m, w01 = tp.w01 * m;
                float w10 = tp.w10 * m, w11 = tp.w11 * m;
                short8 a00 = *(const short8*)(nb2 + (size_t)tp.i00 * 64 + g * 8);
                short8 a01 = *(const short8*)(nb2 + (size_t)tp.i01 * 64 + g * 8);
                short8 a10 = *(const short8*)(nb2 + (size_t)tp.i10 * 64 + g * 8);
                short8 a11 = *(const short8*)(nb2 + (size_t)tp.i11 * 64 + g * 8);
                #pragma unroll
                for (int c = 0; c < 8; ++c) {
                    float s = w00 * bf2f(a00[c]) + w01 * bf2f(a01[c]) +
                              w10 * bf2f(a10[c]) + w11 * bf2f(a11[c]);
                    v[c] = f2bf(s);
                }
            }
            *(short8*)(&ldsA[px * 104 + k * 8]) = v;
        }
        __syncthreads();
        // MFMA phase: K = 96 (3 chunks), wave w owns och-tile w
        #pragma unroll
        for (int kc = 0; kc < 3; ++kc) {
            short8 bfrag = *(const short8*)(wrd +
                ((size_t)(((g * 3 + kc) * 4 + w) * 64 + l15 * 4 + q)) * 8);
            #pragma unroll
            for (int mt = 0; mt < 4; ++mt) {
                short8 a = *(const short8*)(&ldsA[(mt * 16 + l15) * 104 + kc * 32 + q * 8]);
                acc[mt] = __builtin_amdgcn_mfma_f32_16x16x32_bf16(a, bfrag, acc[mt], 0, 0, 0);
            }
        }
    }

    // epilogue: LDS transpose -> coalesced NCHW stores (+bias)
    __syncthreads();
    #pragma unroll
    for (int mt = 0; mt < 4; ++mt)
        #pragma unroll
        for (int rg = 0; rg < 4; ++rg)
            ldsT[(w * 16 + l15) * 65 + mt * 16 + q * 4 + rg] = acc[mt][rg];
    __syncthreads();
    float* ob = out + (size_t)b * 64 * HW + pos0;
    for (int f = tid; f < 4096; f += 256) {
        int och = f >> 6, p2 = f & 63;
        ob[(size_t)och * HW + p2] = ldsT[och * 65 + p2] + bias[och];
    }
}

// ---------------------------------------------------------------------------
extern "C" void kernel_launch(void* const* d_in, const int* in_sizes, int n_in,
                              void* d_out, int out_size, void* d_ws, size_t ws_size,
                              hipStream_t stream)
{
    const float* nbr  = (const float*)d_in[0];
    const float* ref  = (const float*)d_in[1];
    const float* flow = (const float*)d_in[2];
    const float* c1w  = (const float*)d_in[3];
    const float* c1b  = (const float*)d_in[4];
    const float* omw  = (const float*)d_in[5];
    const float* omb  = (const float*)d_in[6];
    const float* dw   = (const float*)d_in[7];
    const float* db   = (const float*)d_in[8];
    float* out = (float*)d_out;

    char* wsb = (char*)d_ws;
    short* X1    = (short*)(wsb);                  // 33,554,432 B
    short* X2    = (short*)(wsb + 33554432);       // 25,165,824 B
    float* omraw = (float*)(wsb + 58720256);       // 113,246,208 B
    short* wr1   = (short*)(wsb + 171966464);      // 147,456 B
    short* wr2   = (short*)(wsb + 172113920);      // 442,368 B
    short* wrd   = (short*)(wsb + 172556288);      // 98,304 B
    // N2 aliases X1: X1 is dead after conv1_mfma; stream serializes kernels.
    short* N2    = X1;                             // 16,777,216 B

    repack_w1_kernel<<<288, 256, 0, stream>>>(c1w, wr1);
    repack_w2_kernel<<<864, 256, 0, stream>>>(omw, wr2);
    repack_dcn_kernel<<<192, 256, 0, stream>>>(dw, wrd);
    pack_x1_kernel<<<2048, 256, 0, stream>>>(nbr, ref, flow, X1);
    pack_x2_flow_kernel<<<512, 256, 0, stream>>>(flow, X2);
    conv1_mfma_kernel<<<2048, 256, 0, stream>>>(X1, c1b, wr1, X2);
    pack_nbr_kernel<<<2048, 256, 0, stream>>>(nbr, N2);   // overwrites X1
    om_mfma_kernel<<<2048, 256, 0, stream>>>(X2, wr2, omb, omraw);
    dcn_mfma_kernel<<<2048, 256, 0, stream>>>(omraw, flow, N2, wrd, db, out);
}

// Round 6
// 444.150 us; speedup vs baseline: 4.7658x; 1.1108x over previous
//
#include <hip/hip_runtime.h>
#include <math.h>

#define HW 65536
#define WD 256
#define HT 256

typedef short short8 __attribute__((ext_vector_type(8)));
typedef float f32x4 __attribute__((ext_vector_type(4)));

__device__ __forceinline__ short f2bf(float f) {
    union { float f; unsigned u; } v; v.f = f;
    unsigned r = (v.u + 0x7fffu + ((v.u >> 16) & 1u)) >> 16;
    return (short)r;
}

__device__ __forceinline__ float bf2f(short s) {
    union { unsigned u; float f; } v;
    v.u = ((unsigned)(unsigned short)s) << 16;
    return v.f;
}

__device__ __forceinline__ int iclamp(int v, int lo, int hi) {
    return v < lo ? lo : (v > hi ? hi : v);
}

struct Taps {
    int i00, i01, i10, i11;
    float w00, w01, w10, w11;
};

__device__ __forceinline__ Taps make_taps(float py, float px) {
    float fy0 = floorf(py), fx0 = floorf(px);
    float wy = py - fy0, wx = px - fx0;
    int y0 = (int)fy0, x0 = (int)fx0;
    int y1 = y0 + 1, x1 = x0 + 1;
    float vy0 = (y0 >= 0 && y0 <= HT - 1) ? 1.f : 0.f;
    float vy1 = (y1 >= 0 && y1 <= HT - 1) ? 1.f : 0.f;
    float vx0 = (x0 >= 0 && x0 <= WD - 1) ? 1.f : 0.f;
    float vx1 = (x1 >= 0 && x1 <= WD - 1) ? 1.f : 0.f;
    int yc0 = iclamp(y0, 0, HT - 1), yc1 = iclamp(y1, 0, HT - 1);
    int xc0 = iclamp(x0, 0, WD - 1), xc1 = iclamp(x1, 0, WD - 1);
    Taps t;
    t.i00 = yc0 * WD + xc0; t.i01 = yc0 * WD + xc1;
    t.i10 = yc1 * WD + xc0; t.i11 = yc1 * WD + xc1;
    t.w00 = (1.f - wy) * (1.f - wx) * vy0 * vx0;
    t.w01 = (1.f - wy) * wx * vy0 * vx1;
    t.w10 = wy * (1.f - wx) * vy1 * vx0;
    t.w11 = wy * wx * vy1 * vx1;
    return t;
}

// ---------------------------------------------------------------------------
// pack_x1: warp(nbr) + ref -> X1 (B,HW,128) NHWC bf16, via LDS transpose.
// ---------------------------------------------------------------------------
__global__ __launch_bounds__(256) void pack_x1_kernel(
    const float* __restrict__ nbr, const float* __restrict__ ref,
    const float* __restrict__ flow, short* __restrict__ X1)
{
    __shared__ short tile[64 * 130];
    int blk = blockIdx.x;              // b*1024 + grp
    int b = blk >> 10;
    int grp = blk & 1023;
    int px = threadIdx.x & 63;
    int qq = threadIdx.x >> 6;
    int pos = grp * 64 + px;
    int yy = pos >> 8, xx = pos & 255;

    float fx = flow[b * 2 * HW + pos];
    float fy = flow[b * 2 * HW + HW + pos];
    Taps tp = make_taps((float)yy + fy, (float)xx + fx);

    const float* nb = nbr + (size_t)b * 64 * HW;
    const float* rf = ref + (size_t)b * 64 * HW;
    #pragma unroll
    for (int j = 0; j < 16; ++j) {
        int c = qq * 16 + j;
        const float* pc = nb + c * HW;
        float v = tp.w00 * pc[tp.i00] + tp.w01 * pc[tp.i01] +
                  tp.w10 * pc[tp.i10] + tp.w11 * pc[tp.i11];
        tile[px * 130 + c] = f2bf(v);
        tile[px * 130 + 64 + c] = f2bf(rf[c * HW + pos]);
    }
    __syncthreads();

    short* xo = X1 + ((size_t)b * HW + grp * 64) * 128;
    #pragma unroll
    for (int f8 = threadIdx.x; f8 < 1024; f8 += 256) {
        int p = (f8 * 8) >> 7;
        int c = (f8 * 8) & 127;
        short8 v;
        #pragma unroll
        for (int j = 0; j < 8; ++j) v[j] = tile[p * 130 + c + j];
        *(short8*)(xo + f8 * 8) = v;
    }
}

// ---------------------------------------------------------------------------
// pack_nbr: nbr (B,64,HW) f32 -> N2 (B,HW,64) bf16 via LDS transpose.
// ---------------------------------------------------------------------------
__global__ __launch_bounds__(256) void pack_nbr_kernel(
    const float* __restrict__ nbr, short* __restrict__ N2)
{
    __shared__ short tile[64 * 66];
    int blk = blockIdx.x;              // b*1024 + grp
    int b = blk >> 10;
    int grp = blk & 1023;
    int px = threadIdx.x & 63;
    int qq = threadIdx.x >> 6;
    int pos = grp * 64 + px;

    const float* nb = nbr + (size_t)b * 64 * HW;
    #pragma unroll
    for (int j = 0; j < 16; ++j) {
        int c = qq * 16 + j;
        tile[px * 66 + c] = f2bf(nb[c * HW + pos]);
    }
    __syncthreads();

    short* xo = N2 + ((size_t)b * HW + grp * 64) * 64;
    #pragma unroll
    for (int f8 = threadIdx.x; f8 < 512; f8 += 256) {
        int p = f8 >> 3;
        int c = (f8 & 7) * 8;
        short8 v;
        #pragma unroll
        for (int j = 0; j < 8; ++j) v[j] = tile[p * 66 + c + j];
        *(short8*)(xo + f8 * 8) = v;
    }
}

// ---------------------------------------------------------------------------
// pack_x2_flow: fill X2 channels 64..95 (flow bf16 + zero pad).
// ---------------------------------------------------------------------------
__global__ __launch_bounds__(256) void pack_x2_flow_kernel(
    const float* __restrict__ flow, short* __restrict__ X2)
{
    int t = blockIdx.x * 256 + threadIdx.x;   // 2*HW
    int b = t >> 16;
    int pos = t & (HW - 1);
    short bx = f2bf(flow[b * 2 * HW + pos]);
    short by = f2bf(flow[b * 2 * HW + HW + pos]);
    short* p = X2 + ((size_t)b * HW + pos) * 96 + 64;
    short8 first = {bx, by, 0, 0, 0, 0, 0, 0};
    short8 z = {0, 0, 0, 0, 0, 0, 0, 0};
    *(short8*)(p) = first;
    *(short8*)(p + 8) = z;
    *(short8*)(p + 16) = z;
    *(short8*)(p + 24) = z;
}

// ---------------------------------------------------------------------------
// Weight repacks to MFMA B-fragment order.
// ---------------------------------------------------------------------------
__global__ __launch_bounds__(256) void repack_w1_kernel(
    const float* __restrict__ w, short* __restrict__ wr)
{
    int t = blockIdx.x * 256 + threadIdx.x;  // 73728
    int j = t & 7, q = (t >> 3) & 3, l = (t >> 5) & 15;
    int nt = (t >> 9) & 3, kc = t >> 11;
    int k = kc * 32 + q * 8 + j;
    int rs = k >> 7, c = k & 127;
    int n = nt * 16 + l;
    wr[t] = f2bf(w[(n * 128 + c) * 9 + rs]);
}

__global__ __launch_bounds__(256) void repack_w2_kernel(
    const float* __restrict__ w, short* __restrict__ wr)
{
    int t = blockIdx.x * 256 + threadIdx.x;  // 221184
    int j = t & 7, q = (t >> 3) & 3, l = (t >> 5) & 15;
    int nt = (t >> 9) & 15, kc = t >> 13;
    int k = kc * 32 + q * 8 + j;
    int rs = k / 96, c = k % 96;
    int n = nt * 16 + l;
    float v = (n < 216 && c < 66) ? w[(n * 66 + c) * 9 + rs] : 0.f;
    wr[t] = f2bf(v);
}

// dcn weights -> B-frag order: flat = (((g*3+kc)*4+nt)*64 + l15*4+q)*8 + j
__global__ __launch_bounds__(256) void repack_dcn_kernel(
    const float* __restrict__ w, short* __restrict__ wr)
{
    int t = blockIdx.x * 256 + threadIdx.x;   // 49152
    int j = t & 7, q = (t >> 3) & 3, l = (t >> 5) & 15;
    int rem = t >> 9;           // (g*3+kc)*4 + nt
    int nt = rem & 3;
    int gkc = rem >> 2;         // g*3 + kc
    int kc = gkc % 3, g = gkc / 3;
    int Kidx = kc * 32 + q * 8 + j;
    int k = Kidx >> 3, c = Kidx & 7;
    int och = nt * 16 + l;
    float v = (k < 9) ? w[(och * 64 + g * 8 + c) * 9 + k] : 0.f;
    wr[t] = f2bf(v);
}

// ---------------------------------------------------------------------------
// conv1 MFMA: X1 (NHWC bf16, 128ch) -> fea ch 0..63 of X2 (NHWC bf16, 96).
// K-loop flattened to 36 chunks with ping/pong B-fragment register prefetch
// (weights are 147 KB -> always L1-miss; prefetch hides ~200cyc L2 latency).
// ---------------------------------------------------------------------------
#define PADC1 136
__global__ __launch_bounds__(256) void conv1_mfma_kernel(
    const short* __restrict__ X1, const float* __restrict__ bias,
    const short* __restrict__ wr, short* __restrict__ X2)
{
    __shared__ short lds[3 * 66 * PADC1];
    const int tid = threadIdx.x;
    const int w = __builtin_amdgcn_readfirstlane(tid >> 6);
    const int l15 = tid & 15;
    const int q = (tid >> 4) & 3;
    const int blk = blockIdx.x;
    const int xseg = blk & 3;
    const int yy = (blk >> 2) & 255;
    const int b = blk >> 10;
    const int x0 = xseg * 64;

    const short* xin = X1 + (size_t)b * HW * 128;
    for (int i = tid; i < 198 * 16; i += 256) {
        int c16 = i & 15;
        int pix = i >> 4;
        int r = pix / 66, xx = pix % 66;
        int gy = yy + r - 1, gx = x0 + xx - 1;
        short8 v = {0, 0, 0, 0, 0, 0, 0, 0};
        if (gy >= 0 && gy < HT && gx >= 0 && gx < WD)
            v = *(const short8*)(xin + ((size_t)((gy << 8) + gx)) * 128 + c16 * 8);
        *(short8*)(&lds[(r * 66 + xx) * PADC1 + c16 * 8]) = v;
    }
    __syncthreads();

    f32x4 acc[4] = {{0,0,0,0},{0,0,0,0},{0,0,0,0},{0,0,0,0}};
    const int bbase = l15 * 4 + q;
    const int abase = l15 * PADC1 + q * 8;

    #define LOADB1(kc_) (*(const short8*)(wr + ((size_t)(((kc_) * 4 + w) * 64 + bbase)) * 8))
    #define COMP1(kc_, bf_) { \
        int rs_ = (kc_) >> 2, cc_ = (kc_) & 3; \
        int r_ = rs_ / 3, s_ = rs_ % 3; \
        int ao_ = (r_ * 66 + s_) * PADC1 + cc_ * 32 + abase; \
        _Pragma("unroll") \
        for (int mt = 0; mt < 4; ++mt) { \
            short8 a_ = *(const short8*)(&lds[ao_ + mt * 16 * PADC1]); \
            acc[mt] = __builtin_amdgcn_mfma_f32_16x16x32_bf16(a_, bf_, acc[mt], 0, 0, 0); \
        } }

    short8 bA = LOADB1(0), bB;
    #pragma unroll 1
    for (int jj = 0; jj < 18; ++jj) {
        int kc0 = 2 * jj;
        bB = LOADB1(kc0 + 1);
        COMP1(kc0, bA);
        int kc2 = kc0 + 2; if (kc2 > 35) kc2 = 35;
        bA = LOADB1(kc2);
        COMP1(kc0 + 1, bB);
    }
    #undef LOADB1
    #undef COMP1

    float bv = bias[w * 16 + l15];
    short* xo = X2 + (size_t)b * HW * 96;
    #pragma unroll
    for (int mt = 0; mt < 4; ++mt) {
        #pragma unroll
        for (int rg = 0; rg < 4; ++rg) {
            int px = x0 + mt * 16 + q * 4 + rg;
            float v = fmaxf(acc[mt][rg] + bv, 0.f);
            xo[((size_t)((yy << 8) + px)) * 96 + w * 16 + l15] = f2bf(v);
        }
    }
}

// ---------------------------------------------------------------------------
// om MFMA: X2 (NHWC bf16, 96ch) -> omraw (B,216,HW) fp32.
// K-loop flattened to 27 chunks, ping/pong prefetch of the 4 B-fragments
// (weights 442 KB -> always L1-miss; hide L2 latency behind 16 MFMAs).
// ---------------------------------------------------------------------------
#define PADC2 104
__global__ __launch_bounds__(256) void om_mfma_kernel(
    const short* __restrict__ X2, const short* __restrict__ wr,
    const float* __restrict__ bias, float* __restrict__ omraw)
{
    __shared__ short lds[3 * 66 * PADC2];
    const int tid = threadIdx.x;
    const int w = __builtin_amdgcn_readfirstlane(tid >> 6);
    const int l15 = tid & 15;
    const int q = (tid >> 4) & 3;
    const int blk = blockIdx.x;
    const int xseg = blk & 3;
    const int yy = (blk >> 2) & 255;
    const int b = blk >> 10;
    const int x0 = xseg * 64;

    const short* xin = X2 + (size_t)b * HW * 96;
    for (int i = tid; i < 198 * 12; i += 256) {
        int pix = i / 12;
        int c8 = i - pix * 12;
        int r = pix / 66, xx = pix % 66;
        int gy = yy + r - 1, gx = x0 + xx - 1;
        short8 v = {0, 0, 0, 0, 0, 0, 0, 0};
        if (gy >= 0 && gy < HT && gx >= 0 && gx < WD)
            v = *(const short8*)(xin + ((size_t)((gy << 8) + gx)) * 96 + c8 * 8);
        *(short8*)(&lds[(r * 66 + xx) * PADC2 + c8 * 8]) = v;
    }
    __syncthreads();

    f32x4 acc[4][4];
    #pragma unroll
    for (int i = 0; i < 4; ++i)
        #pragma unroll
        for (int mt = 0; mt < 4; ++mt) acc[i][mt] = (f32x4){0,0,0,0};

    const int bbase = l15 * 4 + q;
    const int abase = l15 * PADC2 + q * 8;

    #define LOADB2(dst_, kc_) { \
        _Pragma("unroll") \
        for (int i = 0; i < 4; ++i) \
            dst_[i] = *(const short8*)(wr + ((size_t)(((kc_) * 16 + w * 4 + i) * 64 + bbase)) * 8); }
    #define COMP2(kc_, bf_) { \
        int r_ = (kc_) / 9, s_ = ((kc_) / 3) % 3, cc_ = (kc_) % 3; \
        int ao_ = (r_ * 66 + s_) * PADC2 + cc_ * 32 + abase; \
        short8 a_[4]; \
        _Pragma("unroll") \
        for (int mt = 0; mt < 4; ++mt) \
            a_[mt] = *(const short8*)(&lds[ao_ + mt * 16 * PADC2]); \
        _Pragma("unroll") \
        for (int i = 0; i < 4; ++i) \
            _Pragma("unroll") \
            for (int mt = 0; mt < 4; ++mt) \
                acc[i][mt] = __builtin_amdgcn_mfma_f32_16x16x32_bf16(a_[mt], bf_[i], acc[i][mt], 0, 0, 0); }

    short8 bA[4], bB[4];
    LOADB2(bA, 0);
    #pragma unroll 1
    for (int jj = 0; jj < 13; ++jj) {
        int kc0 = 2 * jj;
        LOADB2(bB, kc0 + 1);
        COMP2(kc0, bA);
        LOADB2(bA, kc0 + 2);
        COMP2(kc0 + 1, bB);
    }
    COMP2(26, bA);
    #undef LOADB2
    #undef COMP2

    float* ldsT = (float*)lds;
    const int LT = 67;
    #pragma unroll 1
    for (int pass = 0; pass < 2; ++pass) {
        __syncthreads();
        if ((w >> 1) == pass) {
            int wl = w & 1;
            #pragma unroll
            for (int i = 0; i < 4; ++i) {
                int chl = (wl * 4 + i) * 16 + l15;
                #pragma unroll
                for (int mt = 0; mt < 4; ++mt)
                    #pragma unroll
                    for (int rg = 0; rg < 4; ++rg)
                        ldsT[chl * LT + mt * 16 + q * 4 + rg] = acc[i][mt][rg];
            }
        }
        __syncthreads();
        int chbase = pass * 128;
        for (int f = tid; f < 128 * 64; f += 256) {
            int chl = f >> 6, px = f & 63;
            int ch = chbase + chl;
            if (ch < 216) {
                float v = ldsT[chl * LT + px] + bias[ch];
                omraw[((size_t)b * 216 + ch) * HW + (yy << 8) + x0 + px] = v;
            }
        }
    }
}

// ---------------------------------------------------------------------------
// dcn MFMA: sampled A-tile (64 px x 96 K per group) built in LDS as bf16.
// Gathers read N2 (NHWC bf16): one 16B load covers all 8 group channels.
// ---------------------------------------------------------------------------
__global__ __launch_bounds__(256) void dcn_mfma_kernel(
    const float* __restrict__ raw,    // (B,216,HW)
    const float* __restrict__ flow,   // (B,2,HW)
    const short* __restrict__ N2,     // (B,HW,64) bf16
    const short* __restrict__ wrd,    // B-frag order, 49152
    const float* __restrict__ bias,   // 64
    float* __restrict__ out)          // (B,64,HW)
{
    __shared__ __align__(16) char ldsraw[16640];
    short* ldsA = (short*)ldsraw;     // [64 px][104] (96 used)
    float* ldsT = (float*)ldsraw;     // [64 och][65] epilogue reuse

    const int tid = threadIdx.x;
    const int w = __builtin_amdgcn_readfirstlane(tid >> 6);
    const int l15 = tid & 15;
    const int q = (tid >> 4) & 3;
    const int qq = tid >> 6;
    const int px = tid & 63;

    const int blk = blockIdx.x;
    const int b = blk >> 10;
    const int grp = blk & 1023;
    const int pos0 = grp * 64;
    const int pos = pos0 + px;
    const int yy = pos >> 8, xx = pos & 255;

    const float* rawb = raw + (size_t)b * 216 * HW + pos;
    const float fx = flow[b * 2 * HW + pos];
    const float fy = flow[b * 2 * HW + HW + pos];
    const short* nb2 = N2 + (size_t)b * HW * 64;

    f32x4 acc[4] = {{0,0,0,0},{0,0,0,0},{0,0,0,0},{0,0,0,0}};

    #pragma unroll 1
    for (int g = 0; g < 8; ++g) {
        __syncthreads();   // protect ldsA from previous iteration's reads
        // fill phase: thread handles taps k = qq, qq+4, qq+8 (k>=9 -> zeros)
        #pragma unroll
        for (int it = 0; it < 3; ++it) {
            int k = qq + 4 * it;
            short8 v = {0, 0, 0, 0, 0, 0, 0, 0};
            if (k < 9) {
                float dy = rawb[(g * 18 + 2 * k) * HW] + fy;
                float dx = rawb[(g * 18 + 2 * k + 1) * HW] + fx;
                float mr = rawb[(144 + g * 9 + k) * HW];
                float m = 1.f / (1.f + __expf(-mr));
                float py = (float)(yy - 1 + k / 3) + dy;
                float pxx = (float)(xx - 1 + k % 3) + dx;
                Taps tp = make_taps(py, pxx);
                float w00 = tp.w00 * m, w01 = tp.w01 * m;
                float w10 = tp.w10 * m, w11 = tp.w11 * m;
                short8 a00 = *(const short8*)(nb2 + (size_t)tp.i00 * 64 + g * 8);
                short8 a01 = *(const short8*)(nb2 + (size_t)tp.i01 * 64 + g * 8);
                short8 a10 = *(const short8*)(nb2 + (size_t)tp.i10 * 64 + g * 8);
                short8 a11 = *(const short8*)(nb2 + (size_t)tp.i11 * 64 + g * 8);
                #pragma unroll
                for (int c = 0; c < 8; ++c) {
                    float s = w00 * bf2f(a00[c]) + w01 * bf2f(a01[c]) +
                              w10 * bf2f(a10[c]) + w11 * bf2f(a11[c]);
                    v[c] = f2bf(s);
                }
            }
            *(short8*)(&ldsA[px * 104 + k * 8]) = v;
        }
        __syncthreads();
        // MFMA phase: K = 96 (3 chunks), wave w owns och-tile w
        #pragma unroll
        for (int kc = 0; kc < 3; ++kc) {
            short8 bfrag = *(const short8*)(wrd +
                ((size_t)(((g * 3 + kc) * 4 + w) * 64 + l15 * 4 + q)) * 8);
            #pragma unroll
            for (int mt = 0; mt < 4; ++mt) {
                short8 a = *(const short8*)(&ldsA[(mt * 16 + l15) * 104 + kc * 32 + q * 8]);
                acc[mt] = __builtin_amdgcn_mfma_f32_16x16x32_bf16(a, bfrag, acc[mt], 0, 0, 0);
            }
        }
    }

    // epilogue: LDS transpose -> coalesced NCHW stores (+bias)
    __syncthreads();
    #pragma unroll
    for (int mt = 0; mt < 4; ++mt)
        #pragma unroll
        for (int rg = 0; rg < 4; ++rg)
            ldsT[(w * 16 + l15) * 65 + mt * 16 + q * 4 + rg] = acc[mt][rg];
    __syncthreads();
    float* ob = out + (size_t)b * 64 * HW + pos0;
    for (int f = tid; f < 4096; f += 256) {
        int och = f >> 6, p2 = f & 63;
        ob[(size_t)och * HW + p2] = ldsT[och * 65 + p2] + bias[och];
    }
}

// ---------------------------------------------------------------------------
extern "C" void kernel_launch(void* const* d_in, const int* in_sizes, int n_in,
                              void* d_out, int out_size, void* d_ws, size_t ws_size,
                              hipStream_t stream)
{
    const float* nbr  = (const float*)d_in[0];
    const float* ref  = (const float*)d_in[1];
    const float* flow = (const float*)d_in[2];
    const float* c1w  = (const float*)d_in[3];
    const float* c1b  = (const float*)d_in[4];
    const float* omw  = (const float*)d_in[5];
    const float* omb  = (const float*)d_in[6];
    const float* dw   = (const float*)d_in[7];
    const float* db   = (const float*)d_in[8];
    float* out = (float*)d_out;

    char* wsb = (char*)d_ws;
    short* X1    = (short*)(wsb);                  // 33,554,432 B
    short* X2    = (short*)(wsb + 33554432);       // 25,165,824 B
    float* omraw = (float*)(wsb + 58720256);       // 113,246,208 B
    short* wr1   = (short*)(wsb + 171966464);      // 147,456 B
    short* wr2   = (short*)(wsb + 172113920);      // 442,368 B
    short* wrd   = (short*)(wsb + 172556288);      // 98,304 B
    // N2 aliases X1: X1 is dead after conv1_mfma; stream serializes kernels.
    short* N2    = X1;                             // 16,777,216 B

    repack_w1_kernel<<<288, 256, 0, stream>>>(c1w, wr1);
    repack_w2_kernel<<<864, 256, 0, stream>>>(omw, wr2);
    repack_dcn_kernel<<<192, 256, 0, stream>>>(dw, wrd);
    pack_x1_kernel<<<2048, 256, 0, stream>>>(nbr, ref, flow, X1);
    pack_x2_flow_kernel<<<512, 256, 0, stream>>>(flow, X2);
    conv1_mfma_kernel<<<2048, 256, 0, stream>>>(X1, c1b, wr1, X2);
    pack_nbr_kernel<<<2048, 256, 0, stream>>>(nbr, N2);   // overwrites X1
    om_mfma_kernel<<<2048, 256, 0, stream>>>(X2, wr2, omb, omraw);
    dcn_mfma_kernel<<<2048, 256, 0, stream>>>(omraw, flow, N2, wrd, db, out);
}